// Round 9
// baseline (310.169 us; speedup 1.0000x reference)
//
#include <hip/hip_runtime.h>
#include <hip/hip_bf16.h>
#include <math.h>

#define NN 50000
#define NE 400000

typedef __attribute__((ext_vector_type(8))) short bf16x8;
typedef __attribute__((ext_vector_type(4))) float f32x4;

// ---------------- helpers ----------------
__device__ __forceinline__ float lrelu(float v){ return v > 0.f ? v : 0.2f*v; }
// fast ELU: v>0 ? v : exp(v)-1 via HW v_exp; abs err ~6e-8, far below bf16 quantum
__device__ __forceinline__ float elu1(float v){ return v > 0.f ? v : __expf(v) - 1.0f; }
// fast hardware exp: v_mul (log2e) + v_exp_f32; rel err ~1e-7
__device__ __forceinline__ float fexp(float v){ return __expf(v); }
__device__ __forceinline__ float bflo(unsigned int u){ return __uint_as_float(u << 16); }
__device__ __forceinline__ float bfhi(unsigned int u){ return __uint_as_float(u & 0xffff0000u); }
__device__ __forceinline__ unsigned short f2bf(float f){
  __hip_bfloat16 h = __float2bfloat16(f);
  return *(unsigned short*)&h;
}
__device__ __forceinline__ unsigned int pack2(float lo, float hi){
  return (unsigned int)f2bf(lo) | ((unsigned int)f2bf(hi) << 16);
}

// stage a packed bf16 [64][64] table into LDS with pitch 72 (2-way-free reads)
__device__ __forceinline__ void stage_tab(unsigned short* Wt, const unsigned short* Wb, int tid){
  #pragma unroll
  for(int s = 0; s < 2; s++){
    int c = tid + s*256;           // 512 chunks of 8 elems
    int n = c >> 3, ko = (c & 7)*8;
    *(bf16x8*)&Wt[n*72 + ko] = *(const bf16x8*)&Wb[n*64 + ko];
  }
}

// ---------------- pack weights descriptor ----------------
struct PKS { const float* src; unsigned short* dst; int kshift; int ldw; int col0; };

// ================= PRE: packw(11) | count(1563) | castsum(256) | fold1(1) =================
struct PreP {
  PKS pk[11];
  const int* col; int* cnt;
  const float* x; unsigned short* xb; float* gsum;
  const float* gw1; const float* gas; const float* gad; float* wsd;
};

#define NB_CNT ((NE+255)/256)      // 1563

__global__ __launch_bounds__(256) void k_pre(PreP p){
  __shared__ float part[4][64];
  int b = blockIdx.x, tid = threadIdx.x;
  if(b < 11){
    PKS s = p.pk[b];
    int K = 1 << s.kshift;
    int total = K << 6;
    for(int idx = tid; idx < total; idx += 256){
      int n = idx >> s.kshift, k = idx & (K - 1);
      s.dst[idx] = f2bf(s.src[(size_t)k*s.ldw + s.col0 + n]);
    }
    return;
  }
  if(b < 11 + NB_CNT){
    int e = (b - 11)*256 + tid;
    if(e < NE) atomicAdd(&p.cnt[p.col[e]], 1);
    return;
  }
  if(b < 11 + NB_CNT + 256){
    int lb = b - (11 + NB_CNT);
    int lane = tid & 63, w = tid >> 6;
    float s = 0.f;
    for(int r = lb*4 + w; r < NN; r += 256*4){
      float v = p.x[(size_t)r*64 + lane];
      p.xb[(size_t)r*64 + lane] = f2bf(v);
      s += v;
    }
    part[w][lane] = s;
    __syncthreads();
    if(w == 0) atomicAdd(&p.gsum[lane], part[0][lane]+part[1][lane]+part[2][lane]+part[3][lane]);
    return;
  }
  // fold1
  {
    int k = tid & 63, h = tid >> 6;
    float ssrc = 0.f, sdst = 0.f;
    for(int c = 0; c < 64; c++){
      float w = p.gw1[k*256 + h*64 + c];
      ssrc += w * p.gas[h*64 + c];
      sdst += w * p.gad[h*64 + c];
    }
    p.wsd[k*8 + h] = ssrc;
    p.wsd[k*8 + 4 + h] = sdst;
  }
}

// ---------------- CSR alloc (scan) ----------------
__global__ void k_alloc(const int* __restrict__ cnt, int* __restrict__ offs,
                        float* __restrict__ dis, float* __restrict__ invc,
                        int* __restrict__ total, int N){
  int i = blockIdx.x*blockDim.x + threadIdx.x;
  int lane = threadIdx.x & 63;
  int v = (i < N) ? cnt[i] : 0;
  int x = v;
  #pragma unroll
  for(int d = 1; d < 64; d <<= 1){ int t = __shfl_up(x, d, 64); if(lane >= d) x += t; }
  int base = 0;
  if(lane == 63 && x > 0) base = atomicAdd(total, x);
  base = __shfl(base, 63, 64);
  if(i < N){
    offs[i] = base + x - v;
    dis[i]  = 1.0f / sqrtf((float)(v + 1));
    invc[i] = 1.0f / fmaxf((float)v, 1.0f);
  }
}

// ================= MID: fill(1563) | gate(1) | attdotx(3125) =================
struct MidP {
  const int* row; const int* col; const int* offs; int* cursor; int* csr;
  const float* gsum; const float* w1; const float* b1; const float* w2; const float* b2;
  float* gatew;
  const unsigned short* xb; const float* wsd; float* asrc; float* adst;
};

#define NB_ATT (NN/16)             // 3125

__global__ __launch_bounds__(256) void k_mid(MidP p){
  __shared__ float ws[64*8];
  __shared__ float g[64]; __shared__ float hid[64]; __shared__ float lg[3];
  int b = blockIdx.x, tid = threadIdx.x;
  if(b < NB_CNT){
    int e = b*256 + tid;
    if(e < NE){
      int c = p.col[e];
      int pos = p.offs[c] + atomicAdd(&p.cursor[c], 1);
      p.csr[pos] = p.row[e];
    }
    return;
  }
  if(b == NB_CNT){
    int t = tid;
    if(t < 64) g[t] = p.gsum[t] * (1.0f/(float)NN);
    __syncthreads();
    if(t < 64){
      float acc = p.b1[t];
      for(int i = 0; i < 64; i++) acc += g[i]*p.w1[i*64 + t];
      hid[t] = fmaxf(acc, 0.f);
    }
    __syncthreads();
    if(t < 3){
      float a = p.b2[t];
      for(int j = 0; j < 64; j++) a += hid[j]*p.w2[j*3 + t];
      lg[t] = a;
    }
    __syncthreads();
    if(t == 0){
      float m = fmaxf(lg[0], fmaxf(lg[1], lg[2]));
      float e0 = expf(lg[0]-m), e1 = expf(lg[1]-m), e2 = expf(lg[2]-m);
      float s = e0 + e1 + e2;
      p.gatew[0] = e0/s; p.gatew[1] = e1/s; p.gatew[2] = e2/s;
    }
    return;
  }
  // attdotx
  int lb = b - (NB_CNT + 1);
  ws[tid] = p.wsd[tid];
  ws[tid + 256] = p.wsd[tid + 256];
  __syncthreads();
  int node = lb*16 + (tid >> 4);
  int l = tid & 15;
  if(node >= NN) return;
  uint2 u = *(const uint2*)&p.xb[(size_t)node*64 + l*4];
  float v0 = bflo(u.x), v1 = bfhi(u.x), v2 = bflo(u.y), v3 = bfhi(u.y);
  float s[8];
  #pragma unroll
  for(int h = 0; h < 8; h++){
    s[h] = v0*ws[(l*4+0)*8+h] + v1*ws[(l*4+1)*8+h] + v2*ws[(l*4+2)*8+h] + v3*ws[(l*4+3)*8+h];
  }
  #pragma unroll
  for(int d = 8; d >= 1; d >>= 1){
    #pragma unroll
    for(int h = 0; h < 8; h++) s[h] += __shfl_xor(s[h], d, 16);
  }
  if(l == 0){
    float4 o1; o1.x = s[0]; o1.y = s[1]; o1.z = s[2]; o1.w = s[3];
    float4 o2; o2.x = s[4]; o2.y = s[5]; o2.z = s[6]; o2.w = s[7];
    *(float4*)&p.asrc[node*4] = o1;
    *(float4*)&p.adst[node*4] = o2;
  }
}

// ================= AGG1: layer-1 gather, GAT1 edge weights inline (1 node/wave) =================
struct A1P {
  const unsigned short* xb; const float* asrc1; const float* adst1;
  const int* offs; const int* cnt; const int* csr;
  const float* dis; const float* invc;
  unsigned short* z; unsigned short* agcnx; unsigned short* asagex; int N;
};

__global__ void k_agg1(A1P p){
  int node = blockIdx.x*4 + (threadIdx.x >> 6);
  int lane = threadIdx.x & 63;
  if(node >= p.N) return;
  int half = lane >> 5, subl = lane & 31;
  float4 ad4 = *(const float4*)&p.adst1[node*4];
  float zg[4][2] = {{0,0},{0,0},{0,0},{0,0}};
  float gg[2] = {0,0}, ssv[2] = {0,0}, wsum[4] = {0,0,0,0};
  int e0 = p.offs[node], e1 = e0 + p.cnt[node];
  #pragma unroll 4
  for(int e = e0 + half; e < e1; e += 2){
    int s = p.csr[e];
    float4 as4 = *(const float4*)&p.asrc1[s*4];
    float ds = p.dis[s];
    unsigned int u = *(const unsigned int*)&p.xb[(size_t)s*64 + subl*2];
    float w0 = fexp(lrelu(as4.x + ad4.x));
    float w1 = fexp(lrelu(as4.y + ad4.y));
    float w2 = fexp(lrelu(as4.z + ad4.z));
    float w3 = fexp(lrelu(as4.w + ad4.w));
    float xl = bflo(u), xh = bfhi(u);
    zg[0][0] = fmaf(w0, xl, zg[0][0]); zg[0][1] = fmaf(w0, xh, zg[0][1]);
    zg[1][0] = fmaf(w1, xl, zg[1][0]); zg[1][1] = fmaf(w1, xh, zg[1][1]);
    zg[2][0] = fmaf(w2, xl, zg[2][0]); zg[2][1] = fmaf(w2, xh, zg[2][1]);
    zg[3][0] = fmaf(w3, xl, zg[3][0]); zg[3][1] = fmaf(w3, xh, zg[3][1]);
    gg[0] = fmaf(ds, xl, gg[0]); gg[1] = fmaf(ds, xh, gg[1]);
    ssv[0] += xl; ssv[1] += xh;
    wsum[0] += w0; wsum[1] += w1; wsum[2] += w2; wsum[3] += w3;
  }
  #pragma unroll
  for(int h = 0; h < 4; h++){
    zg[h][0] += __shfl_xor(zg[h][0], 32, 64);
    zg[h][1] += __shfl_xor(zg[h][1], 32, 64);
    wsum[h]  += __shfl_xor(wsum[h], 32, 64);
  }
  gg[0] += __shfl_xor(gg[0], 32, 64); gg[1] += __shfl_xor(gg[1], 32, 64);
  ssv[0] += __shfl_xor(ssv[0], 32, 64); ssv[1] += __shfl_xor(ssv[1], 32, 64);
  if(half == 0){
    unsigned int un = *(const unsigned int*)&p.xb[(size_t)node*64 + subl*2];
    float xl = bflo(un), xh = bfhi(un);
    float4 asn = *(const float4*)&p.asrc1[node*4];
    float s0 = fexp(lrelu(asn.x + ad4.x));
    float s1v = fexp(lrelu(asn.y + ad4.y));
    float s2 = fexp(lrelu(asn.z + ad4.z));
    float s3 = fexp(lrelu(asn.w + ad4.w));
    float rd0 = 1.0f/(wsum[0] + s0), rd1 = 1.0f/(wsum[1] + s1v);
    float rd2 = 1.0f/(wsum[2] + s2), rd3 = 1.0f/(wsum[3] + s3);
    unsigned int* zp = (unsigned int*)&p.z[(size_t)node*256 + subl*2];
    zp[0]  = pack2((zg[0][0] + s0*xl)*rd0,  (zg[0][1] + s0*xh)*rd0);
    zp[32] = pack2((zg[1][0] + s1v*xl)*rd1, (zg[1][1] + s1v*xh)*rd1);
    zp[64] = pack2((zg[2][0] + s2*xl)*rd2,  (zg[2][1] + s2*xh)*rd2);
    zp[96] = pack2((zg[3][0] + s3*xl)*rd3,  (zg[3][1] + s3*xh)*rd3);
    float dc = p.dis[node], ic = p.invc[node];
    *(unsigned int*)&p.agcnx[(size_t)node*64 + subl*2] =
        pack2(dc*fmaf(dc, xl, gg[0]), dc*fmaf(dc, xh, gg[1]));
    *(unsigned int*)&p.asagex[(size_t)node*64 + subl*2] = pack2(ssv[0]*ic, ssv[1]*ic);
  }
}

// ================= AGG2: layer-2 gather, GAT2 edge weights inline (1 node/wave) =================
struct A2P {
  const unsigned short* a1; const unsigned short* s1; const unsigned short* h2;
  const float* asrc2; const float* adst2;
  const int* offs; const int* cnt; const int* csr;
  const float* dis; const float* invc;
  unsigned short* A2agg; unsigned short* S2agg; unsigned short* T2; int N;
};

__global__ void k_agg2(A2P p){
  int node = blockIdx.x*4 + (threadIdx.x >> 6);
  int lane = threadIdx.x & 63;
  if(node >= p.N) return;
  int half = lane >> 5, subl = lane & 31;
  float ad = p.adst2[node];
  float aa[2] = {0,0}, ss[2] = {0,0}, tt[2] = {0,0}, wsum = 0.f;
  int e0 = p.offs[node], e1 = e0 + p.cnt[node];
  #pragma unroll 4
  for(int e = e0 + half; e < e1; e += 2){
    int s = p.csr[e];
    float wv = fexp(lrelu(p.asrc2[s] + ad));
    float ds = p.dis[s];
    unsigned int ua = *(const unsigned int*)&p.a1[(size_t)s*64 + subl*2];
    unsigned int us = *(const unsigned int*)&p.s1[(size_t)s*64 + subl*2];
    unsigned int uh = *(const unsigned int*)&p.h2[(size_t)s*64 + subl*2];
    aa[0] = fmaf(ds, bflo(ua), aa[0]); aa[1] = fmaf(ds, bfhi(ua), aa[1]);
    ss[0] += bflo(us); ss[1] += bfhi(us);
    tt[0] = fmaf(wv, bflo(uh), tt[0]); tt[1] = fmaf(wv, bfhi(uh), tt[1]);
    wsum += wv;
  }
  aa[0] += __shfl_xor(aa[0], 32, 64); aa[1] += __shfl_xor(aa[1], 32, 64);
  ss[0] += __shfl_xor(ss[0], 32, 64); ss[1] += __shfl_xor(ss[1], 32, 64);
  tt[0] += __shfl_xor(tt[0], 32, 64); tt[1] += __shfl_xor(tt[1], 32, 64);
  wsum  += __shfl_xor(wsum, 32, 64);
  if(half == 0){
    float wss = fexp(lrelu(p.asrc2[node] + ad));
    float rd = 1.0f/(wsum + wss);
    unsigned int uan = *(const unsigned int*)&p.a1[(size_t)node*64 + subl*2];
    unsigned int uhn = *(const unsigned int*)&p.h2[(size_t)node*64 + subl*2];
    float dc = p.dis[node], ic = p.invc[node];
    *(unsigned int*)&p.A2agg[(size_t)node*64 + subl*2] =
        pack2(dc*fmaf(dc, bflo(uan), aa[0]), dc*fmaf(dc, bfhi(uan), aa[1]));
    *(unsigned int*)&p.S2agg[(size_t)node*64 + subl*2] = pack2(ss[0]*ic, ss[1]*ic);
    *(unsigned int*)&p.T2[(size_t)node*64 + subl*2] =
        pack2(fmaf(wss, bflo(uhn), tt[0])*rd, fmaf(wss, bfhi(uhn), tt[1])*rd);
  }
}

// ---------------- fused dispatch: y=0 GAT1+2, y=1 GCN1 mm, y=2 SAGE1 mm ----------------
struct MME {
  const unsigned short* A; const unsigned short* Wb;
  const unsigned short* A2; const unsigned short* Wb2;  // optional second segment (K2=64)
  unsigned short* C;
  const float* b; const float* p1; const float* p2;
  int ep;                                               // 1 = BN+relu; 3 = sage
};
struct FSP {
  const unsigned short* z; const unsigned short* wb1; const float* b1;
  const unsigned short* wb2; const float* as2; const float* ad2;
  unsigned short* h2; float* asrc2; float* adst2;
  MME mm[2];
  int N;
};

// GAT slice: per-head interleave with WAVE-LOCAL 16x72 LDS tile (no barrier needed:
// each wave writes and reads only its own rows; DS ops are wave-ordered via lgkmcnt).
// LDS: GAT needs 4 waves x 16 x 72 u16 = 4608 u16; mm needs 2 tables x 4608 u16.
// Total smem = 9216 u16 = 18432 B -> LDS no longer caps occupancy (wave-slot cap: 8 blk/CU).
__global__ __launch_bounds__(256, 4) void k_fused1(FSP p){
  __shared__ unsigned short smem[9216];
  const int N = p.N;
  int tid = threadIdx.x;
  int w = tid >> 6, lane = tid & 63, quad = lane >> 4, m16 = lane & 15;
  int rowa = blockIdx.x*64 + w*16 + m16;
  int rowc = rowa < N ? rowa : N - 1;
  int robase = blockIdx.x*64 + w*16 + quad*4;

  if(blockIdx.y == 0){
    // ================= GAT layer1+layer2, barrier-free =================
    unsigned short* GHW = smem + w*1152;   // wave-local 16 rows, pitch 72
    f32x4 acc2[4];
    #pragma unroll
    for(int t = 0; t < 4; t++){ acc2[t][0]=0.f; acc2[t][1]=0.f; acc2[t][2]=0.f; acc2[t][3]=0.f; }
    #pragma unroll
    for(int h = 0; h < 4; h++){
      // phase A (head h): z_h @ W1h + b -> ELU -> wave tile
      bf16x8 a0 = *(const bf16x8*)&p.z[(size_t)rowc*256 + h*64 + quad*8];
      bf16x8 a1 = *(const bf16x8*)&p.z[(size_t)rowc*256 + h*64 + 32 + quad*8];
      f32x4 acc[4];
      #pragma unroll
      for(int t = 0; t < 4; t++){ acc[t][0]=0.f; acc[t][1]=0.f; acc[t][2]=0.f; acc[t][3]=0.f; }
      #pragma unroll
      for(int t = 0; t < 4; t++){
        const unsigned short* wb = p.wb1 + (size_t)h*4096 + (t*16 + m16)*64;
        bf16x8 b0 = *(const bf16x8*)&wb[quad*8];
        bf16x8 b1v = *(const bf16x8*)&wb[32 + quad*8];
        acc[t] = __builtin_amdgcn_mfma_f32_16x16x32_bf16(a0, b0, acc[t], 0, 0, 0);
        acc[t] = __builtin_amdgcn_mfma_f32_16x16x32_bf16(a1, b1v, acc[t], 0, 0, 0);
      }
      #pragma unroll
      for(int t = 0; t < 4; t++){
        float bv = p.b1[h*64 + t*16 + m16];
        #pragma unroll
        for(int r = 0; r < 4; r++){
          GHW[(quad*4 + r)*72 + t*16 + m16] = f2bf(elu1(acc[t][r] + bv));
        }
      }
      // phase B (head h): tile(16x64) @ W2[h*64.., :] accumulating into acc2
      bf16x8 g0 = *(const bf16x8*)&GHW[m16*72 + quad*8];
      bf16x8 g1 = *(const bf16x8*)&GHW[m16*72 + 32 + quad*8];
      #pragma unroll
      for(int t = 0; t < 4; t++){
        const unsigned short* wb = p.wb2 + (size_t)(t*16 + m16)*256 + h*64;
        bf16x8 b0 = *(const bf16x8*)&wb[quad*8];
        bf16x8 b1v = *(const bf16x8*)&wb[32 + quad*8];
        acc2[t] = __builtin_amdgcn_mfma_f32_16x16x32_bf16(g0, b0, acc2[t], 0, 0, 0);
        acc2[t] = __builtin_amdgcn_mfma_f32_16x16x32_bf16(g1, b1v, acc2[t], 0, 0, 0);
      }
    }
    // epilogue: store h2 (bf16) + attention dots
    #pragma unroll
    for(int t = 0; t < 4; t++){
      int col = t*16 + m16;
      #pragma unroll
      for(int r = 0; r < 4; r++){
        int ro = robase + r;
        if(ro < N) p.h2[(size_t)ro*64 + col] = f2bf(acc2[t][r]);
      }
    }
    float ps[4] = {0,0,0,0}, pd[4] = {0,0,0,0};
    #pragma unroll
    for(int t = 0; t < 4; t++){
      int col = t*16 + m16;
      float a_ = p.as2[col], d_ = p.ad2[col];
      #pragma unroll
      for(int r = 0; r < 4; r++){ ps[r] = fmaf(acc2[t][r], a_, ps[r]); pd[r] = fmaf(acc2[t][r], d_, pd[r]); }
    }
    #pragma unroll
    for(int d = 8; d >= 1; d >>= 1){
      #pragma unroll
      for(int r = 0; r < 4; r++){ ps[r] += __shfl_xor(ps[r], d, 64); pd[r] += __shfl_xor(pd[r], d, 64); }
    }
    if(m16 == 0){
      #pragma unroll
      for(int r = 0; r < 4; r++){
        int ro = robase + r;
        if(ro < N){ p.asrc2[ro] = ps[r]; p.adst2[ro] = pd[r]; }
      }
    }
    return;
  }

  // ================= GCN / SAGE layer-1 matmuls (LDS-staged B) =================
  MME m = p.mm[blockIdx.y - 1];
  unsigned short* Wt  = smem;
  unsigned short* Wt2 = smem + 4608;
  stage_tab(Wt, m.Wb, tid);
  if(m.Wb2) stage_tab(Wt2, m.Wb2, tid);
  __syncthreads();
  f32x4 acc[4];
  #pragma unroll
  for(int t = 0; t < 4; t++){ acc[t][0]=0.f; acc[t][1]=0.f; acc[t][2]=0.f; acc[t][3]=0.f; }
  {
    bf16x8 a0 = *(const bf16x8*)&m.A[(size_t)rowc*64 + quad*8];
    bf16x8 a1 = *(const bf16x8*)&m.A[(size_t)rowc*64 + 32 + quad*8];
    #pragma unroll
    for(int t = 0; t < 4; t++){
      bf16x8 b0 = *(const bf16x8*)&Wt[(t*16 + m16)*72 + quad*8];
      bf16x8 b1 = *(const bf16x8*)&Wt[(t*16 + m16)*72 + 32 + quad*8];
      acc[t] = __builtin_amdgcn_mfma_f32_16x16x32_bf16(a0, b0, acc[t], 0, 0, 0);
      acc[t] = __builtin_amdgcn_mfma_f32_16x16x32_bf16(a1, b1, acc[t], 0, 0, 0);
    }
  }
  if(m.A2){
    bf16x8 a0 = *(const bf16x8*)&m.A2[(size_t)rowc*64 + quad*8];
    bf16x8 a1 = *(const bf16x8*)&m.A2[(size_t)rowc*64 + 32 + quad*8];
    #pragma unroll
    for(int t = 0; t < 4; t++){
      bf16x8 b0 = *(const bf16x8*)&Wt2[(t*16 + m16)*72 + quad*8];
      bf16x8 b1 = *(const bf16x8*)&Wt2[(t*16 + m16)*72 + 32 + quad*8];
      acc[t] = __builtin_amdgcn_mfma_f32_16x16x32_bf16(a0, b0, acc[t], 0, 0, 0);
      acc[t] = __builtin_amdgcn_mfma_f32_16x16x32_bf16(a1, b1, acc[t], 0, 0, 0);
    }
  }
  if(m.ep == 3){
    float v[4][4], n2[4] = {0,0,0,0};
    #pragma unroll
    for(int t = 0; t < 4; t++){
      float bv = m.b[t*16 + m16];
      #pragma unroll
      for(int r = 0; r < 4; r++){ v[t][r] = acc[t][r] + bv; n2[r] = fmaf(v[t][r], v[t][r], n2[r]); }
    }
    #pragma unroll
    for(int d = 8; d >= 1; d >>= 1){
      #pragma unroll
      for(int r = 0; r < 4; r++) n2[r] += __shfl_xor(n2[r], d, 64);
    }
    float inv[4];
    #pragma unroll
    for(int r = 0; r < 4; r++) inv[r] = 1.0f / fmaxf(sqrtf(n2[r]), 1e-12f);
    #pragma unroll
    for(int t = 0; t < 4; t++){
      #pragma unroll
      for(int r = 0; r < 4; r++){
        int ro = robase + r;
        if(ro < N) m.C[(size_t)ro*64 + t*16 + m16] = f2bf(fmaxf(v[t][r]*inv[r], 0.f));
      }
    }
    return;
  }
  // ep == 1: BN + relu
  #pragma unroll
  for(int t = 0; t < 4; t++){
    int col = t*16 + m16;
    float bv = m.b[col];
    float gm = m.p1[col]*rsqrtf(1.0f + 1e-5f);
    float be = m.p2[col];
    #pragma unroll
    for(int r = 0; r < 4; r++){
      int ro = robase + r;
      if(ro < N){
        m.C[(size_t)ro*64 + col] = f2bf(fmaxf((acc[t][r] + bv)*gm + be, 0.f));
      }
    }
  }
}

// ---------------- final: GCN2 mm + SAGE2 dual mm + L2norm + GAT2 add + gate combine ----------------
__global__ __launch_bounds__(256) void k_mm_final(
    const unsigned short* __restrict__ A2agg, const unsigned short* __restrict__ wb_gcn2,
    const float* __restrict__ gcn_b2,
    const unsigned short* __restrict__ S2agg, const unsigned short* __restrict__ wb_wl2,
    const float* __restrict__ bl2,
    const unsigned short* __restrict__ s1, const unsigned short* __restrict__ wb_wr2,
    const unsigned short* __restrict__ T2, const float* __restrict__ gat_b2,
    const float* __restrict__ gatew, float* __restrict__ out, int N){
  __shared__ unsigned short W1s[64*72];
  __shared__ unsigned short W2s[64*72];
  __shared__ unsigned short W3s[64*72];
  int tid = threadIdx.x;
  stage_tab(W1s, wb_gcn2, tid);
  stage_tab(W2s, wb_wl2, tid);
  stage_tab(W3s, wb_wr2, tid);
  __syncthreads();
  int w = tid >> 6, lane = tid & 63, quad = lane >> 4, m16 = lane & 15;
  int rowa = blockIdx.x*64 + w*16 + m16;
  int rowc = rowa < N ? rowa : N - 1;
  f32x4 accg[4], accs[4];
  #pragma unroll
  for(int t = 0; t < 4; t++){
    accg[t][0]=0.f; accg[t][1]=0.f; accg[t][2]=0.f; accg[t][3]=0.f;
    accs[t][0]=0.f; accs[t][1]=0.f; accs[t][2]=0.f; accs[t][3]=0.f;
  }
  {
    bf16x8 a0 = *(const bf16x8*)&A2agg[(size_t)rowc*64 + quad*8];
    bf16x8 a1 = *(const bf16x8*)&A2agg[(size_t)rowc*64 + 32 + quad*8];
    #pragma unroll
    for(int t = 0; t < 4; t++){
      bf16x8 b0 = *(const bf16x8*)&W1s[(t*16 + m16)*72 + quad*8];
      bf16x8 b1 = *(const bf16x8*)&W1s[(t*16 + m16)*72 + 32 + quad*8];
      accg[t] = __builtin_amdgcn_mfma_f32_16x16x32_bf16(a0, b0, accg[t], 0, 0, 0);
      accg[t] = __builtin_amdgcn_mfma_f32_16x16x32_bf16(a1, b1, accg[t], 0, 0, 0);
    }
  }
  {
    bf16x8 a0 = *(const bf16x8*)&S2agg[(size_t)rowc*64 + quad*8];
    bf16x8 a1 = *(const bf16x8*)&S2agg[(size_t)rowc*64 + 32 + quad*8];
    #pragma unroll
    for(int t = 0; t < 4; t++){
      bf16x8 b0 = *(const bf16x8*)&W2s[(t*16 + m16)*72 + quad*8];
      bf16x8 b1 = *(const bf16x8*)&W2s[(t*16 + m16)*72 + 32 + quad*8];
      accs[t] = __builtin_amdgcn_mfma_f32_16x16x32_bf16(a0, b0, accs[t], 0, 0, 0);
      accs[t] = __builtin_amdgcn_mfma_f32_16x16x32_bf16(a1, b1, accs[t], 0, 0, 0);
    }
  }
  {
    bf16x8 a0 = *(const bf16x8*)&s1[(size_t)rowc*64 + quad*8];
    bf16x8 a1 = *(const bf16x8*)&s1[(size_t)rowc*64 + 32 + quad*8];
    #pragma unroll
    for(int t = 0; t < 4; t++){
      bf16x8 b0 = *(const bf16x8*)&W3s[(t*16 + m16)*72 + quad*8];
      bf16x8 b1 = *(const bf16x8*)&W3s[(t*16 + m16)*72 + 32 + quad*8];
      accs[t] = __builtin_amdgcn_mfma_f32_16x16x32_bf16(a0, b0, accs[t], 0, 0, 0);
      accs[t] = __builtin_amdgcn_mfma_f32_16x16x32_bf16(a1, b1, accs[t], 0, 0, 0);
    }
  }
  float w0 = gatew[0], w1 = gatew[1], w2 = gatew[2];
  int robase = blockIdx.x*64 + w*16 + quad*4;
  float vs[4][4], n2[4] = {0,0,0,0};
  #pragma unroll
  for(int t = 0; t < 4; t++){
    float bsv = bl2[t*16 + m16];
    #pragma unroll
    for(int r = 0; r < 4; r++){ vs[t][r] = accs[t][r] + bsv; n2[r] = fmaf(vs[t][r], vs[t][r], n2[r]); }
  }
  #pragma unroll
  for(int d = 8; d >= 1; d >>= 1){
    #pragma unroll
    for(int r = 0; r < 4; r++) n2[r] += __shfl_xor(n2[r], d, 64);
  }
  float inv[4];
  #pragma unroll
  for(int r = 0; r < 4; r++) inv[r] = 1.0f / fmaxf(sqrtf(n2[r]), 1e-12f);
  #pragma unroll
  for(int t = 0; t < 4; t++){
    int col = t*16 + m16;
    float bg = gcn_b2[col], bt = gat_b2[col];
    #pragma unroll
    for(int r = 0; r < 4; r++){
      int ro = robase + r;
      if(ro < N){
        float t2 = bflo((unsigned int)T2[(size_t)ro*64 + col]);
        out[(size_t)ro*64 + col] = w0*(accg[t][r] + bg) + w1*(t2 + bt) + w2*vs[t][r]*inv[r];
      }
    }
  }
}

// ---------------- host ----------------
extern "C" void kernel_launch(void* const* d_in, const int* in_sizes, int n_in,
                              void* d_out, int out_size, void* d_ws, size_t ws_size,
                              hipStream_t stream){
  const float* x        = (const float*)d_in[0];
  const int*   ei       = (const int*)d_in[1];
  const int*   row      = ei;
  const int*   col      = ei + NE;
  const float* gate_w1  = (const float*)d_in[2];
  const float* gate_b1  = (const float*)d_in[3];
  const float* gate_w2  = (const float*)d_in[4];
  const float* gate_b2  = (const float*)d_in[5];
  const float* gcn_w1   = (const float*)d_in[6];
  const float* gcn_b1   = (const float*)d_in[7];
  const float* bn_gamma = (const float*)d_in[8];
  const float* bn_beta  = (const float*)d_in[9];
  const float* gcn_w2   = (const float*)d_in[10];
  const float* gcn_b2   = (const float*)d_in[11];
  const float* gat_w1   = (const float*)d_in[12];
  const float* gat_as1  = (const float*)d_in[13];
  const float* gat_ad1  = (const float*)d_in[14];
  const float* gat_b1   = (const float*)d_in[15];
  const float* gat_w2   = (const float*)d_in[16];
  const float* gat_as2  = (const float*)d_in[17];
  const float* gat_ad2  = (const float*)d_in[18];
  const float* gat_b2   = (const float*)d_in[19];
  const float* sage_wl1 = (const float*)d_in[20];
  const float* sage_bl1 = (const float*)d_in[21];
  const float* sage_wr1 = (const float*)d_in[22];
  const float* sage_wl2 = (const float*)d_in[23];
  const float* sage_bl2 = (const float*)d_in[24];
  const float* sage_wr2 = (const float*)d_in[25];
  float* out = (float*)d_out;

  char* wp = (char*)d_ws;
  auto alloc = [&](size_t bytes)->char*{ char* p = wp; wp += (bytes + 255) & ~(size_t)255; return p; };
  // zero-init region (contiguous): cnt, cursor, gsum, total
  int*   cnt    = (int*)  alloc((size_t)NN*4);
  int*   cursor = (int*)  alloc((size_t)NN*4);
  float* gsum   = (float*)alloc(64*4);
  int*   total  = (int*)  alloc(256);
  size_t zbytes = (size_t)(wp - (char*)cnt);
  int*   offs   = (int*)  alloc((size_t)NN*4);
  int*   csr    = (int*)  alloc((size_t)NE*4);
  float* dis    = (float*)alloc((size_t)NN*4);
  float* invc   = (float*)alloc((size_t)NN*4);
  float* gatew  = (float*)alloc(16);
  float* wsd    = (float*)alloc(64*8*4);
  float* asrc1  = (float*)alloc((size_t)NN*4*4);
  float* adst1  = (float*)alloc((size_t)NN*4*4);
  float* asrc2  = (float*)alloc((size_t)NN*4);
  float* adst2  = (float*)alloc((size_t)NN*4);
  unsigned short* xb     = (unsigned short*)alloc((size_t)NN*64*2);
  unsigned short* z      = (unsigned short*)alloc((size_t)NN*256*2);
  unsigned short* agcnx  = (unsigned short*)alloc((size_t)NN*64*2);
  unsigned short* asagex = (unsigned short*)alloc((size_t)NN*64*2);
  unsigned short* a1     = (unsigned short*)alloc((size_t)NN*64*2);
  unsigned short* s1     = (unsigned short*)alloc((size_t)NN*64*2);
  unsigned short* h2     = (unsigned short*)alloc((size_t)NN*64*2);
  unsigned short* A2agg  = (unsigned short*)alloc((size_t)NN*64*2);
  unsigned short* S2agg  = (unsigned short*)alloc((size_t)NN*64*2);
  unsigned short* T2     = (unsigned short*)alloc((size_t)NN*64*2);
  // packed bf16 weights (B-operand layout [n][K])
  unsigned short* wb_gcn1 = (unsigned short*)alloc((size_t)64*64*2);
  unsigned short* wb_wl1  = (unsigned short*)alloc((size_t)64*64*2);
  unsigned short* wb_wr1  = (unsigned short*)alloc((size_t)64*64*2);
  unsigned short* wb_gat1 = (unsigned short*)alloc((size_t)256*64*2);
  unsigned short* wb_gat2 = (unsigned short*)alloc((size_t)64*256*2);
  unsigned short* wb_gcn2 = (unsigned short*)alloc((size_t)64*64*2);
  unsigned short* wb_wl2  = (unsigned short*)alloc((size_t)64*64*2);
  unsigned short* wb_wr2  = (unsigned short*)alloc((size_t)64*64*2);

  hipMemsetAsync(cnt, 0, zbytes, stream);

  const int gN  = (NN + 63) / 64;   // 782
  const int g4  = NN / 4;           // 12500
  const int gA  = (NN + 255) / 256; // 196

  // ---- pre: packw | count | castsum | fold1 ----
  {
    PreP p = {};
    p.pk[0]  = {gcn_w1,   wb_gcn1,            6, 64,  0};
    p.pk[1]  = {sage_wl1, wb_wl1,             6, 64,  0};
    p.pk[2]  = {sage_wr1, wb_wr1,             6, 64,  0};
    p.pk[3]  = {gat_w1,   wb_gat1 + 0*64*64,  6, 256, 0};
    p.pk[4]  = {gat_w1,   wb_gat1 + 1*64*64,  6, 256, 64};
    p.pk[5]  = {gat_w1,   wb_gat1 + 2*64*64,  6, 256, 128};
    p.pk[6]  = {gat_w1,   wb_gat1 + 3*64*64,  6, 256, 192};
    p.pk[7]  = {gat_w2,   wb_gat2,            8, 64,  0};
    p.pk[8]  = {gcn_w2,   wb_gcn2,            6, 64,  0};
    p.pk[9]  = {sage_wl2, wb_wl2,             6, 64,  0};
    p.pk[10] = {sage_wr2, wb_wr2,             6, 64,  0};
    p.col = col; p.cnt = cnt;
    p.x = x; p.xb = xb; p.gsum = gsum;
    p.gw1 = gat_w1; p.gas = gat_as1; p.gad = gat_ad1; p.wsd = wsd;
    k_pre<<<11 + NB_CNT + 256 + 1, 256, 0, stream>>>(p);
  }

  k_alloc<<<gA, 256, 0, stream>>>(cnt, offs, dis, invc, total, NN);

  // ---- mid: fill | gate | attdotx ----
  {
    MidP p = {};
    p.row = row; p.col = col; p.offs = offs; p.cursor = cursor; p.csr = csr;
    p.gsum = gsum; p.w1 = gate_w1; p.b1 = gate_b1; p.w2 = gate_w2; p.b2 = gate_b2;
    p.gatew = gatew;
    p.xb = xb; p.wsd = wsd; p.asrc = asrc1; p.adst = adst1;
    k_mid<<<NB_CNT + 1 + NB_ATT, 256, 0, stream>>>(p);
  }

  // ---- layer-1 gather with inline GAT1 edge weights ----
  {
    A1P p = {};
    p.xb = xb; p.asrc1 = asrc1; p.adst1 = adst1;
    p.offs = offs; p.cnt = cnt; p.csr = csr; p.dis = dis; p.invc = invc;
    p.z = z; p.agcnx = agcnx; p.asagex = asagex; p.N = NN;
    k_agg1<<<g4, 256, 0, stream>>>(p);
  }

  // ---- fused: GAT1+GAT2 (y=0), GCN1 mm (y=1), SAGE1 mm (y=2) ----
  {
    FSP p = {};
    p.N = NN;
    p.z = z; p.wb1 = wb_gat1; p.b1 = gat_b1;
    p.wb2 = wb_gat2; p.as2 = gat_as2; p.ad2 = gat_ad2;
    p.h2 = h2; p.asrc2 = asrc2; p.adst2 = adst2;
    p.mm[0] = {agcnx, wb_gcn1, nullptr, nullptr, a1, gcn_b1, bn_gamma, bn_beta, 1};
    p.mm[1] = {asagex, wb_wl1, xb, wb_wr1, s1, sage_bl1, nullptr, nullptr, 3};
    k_fused1<<<dim3(gN,3), 256, 0, stream>>>(p);
  }

  // ---- layer-2 gather with inline GAT2 edge weights ----
  {
    A2P p = {};
    p.a1 = a1; p.s1 = s1; p.h2 = h2; p.asrc2 = asrc2; p.adst2 = adst2;
    p.offs = offs; p.cnt = cnt; p.csr = csr; p.dis = dis; p.invc = invc;
    p.A2agg = A2agg; p.S2agg = S2agg; p.T2 = T2; p.N = NN;
    k_agg2<<<g4, 256, 0, stream>>>(p);
  }

  // ---- final matmuls + gate combine ----
  k_mm_final<<<gN, 256, 0, stream>>>(A2agg, wb_gcn2, gcn_b2, S2agg, wb_wl2, sage_bl2,
                                     s1, wb_wr2, T2, gat_b2, gatew, out, NN);
}

// Round 10
// 310.106 us; speedup vs baseline: 1.0002x; 1.0002x over previous
//
#include <hip/hip_runtime.h>
#include <hip/hip_bf16.h>
#include <math.h>

#define NN 50000
#define NE 400000

typedef __attribute__((ext_vector_type(8))) short bf16x8;
typedef __attribute__((ext_vector_type(4))) float f32x4;

// GH LDS pitch: row payload is 256 elems (4 heads x 64); min 16B-aligned pitch > 256 is 264.
#define GHP 264

// ---------------- helpers ----------------
__device__ __forceinline__ float lrelu(float v){ return v > 0.f ? v : 0.2f*v; }
// fast ELU via HW v_exp; abs err ~6e-8, far below bf16 quantum
__device__ __forceinline__ float elu1(float v){ return v > 0.f ? v : __expf(v) - 1.0f; }
// fast hardware exp: v_mul (log2e) + v_exp_f32; rel err ~1e-7
__device__ __forceinline__ float fexp(float v){ return __expf(v); }
__device__ __forceinline__ float bflo(unsigned int u){ return __uint_as_float(u << 16); }
__device__ __forceinline__ float bfhi(unsigned int u){ return __uint_as_float(u & 0xffff0000u); }
__device__ __forceinline__ unsigned short f2bf(float f){
  __hip_bfloat16 h = __float2bfloat16(f);
  return *(unsigned short*)&h;
}
__device__ __forceinline__ unsigned int pack2(float lo, float hi){
  return (unsigned int)f2bf(lo) | ((unsigned int)f2bf(hi) << 16);
}

// stage a packed bf16 [64][64] table into LDS with pitch 72 (2-way-free reads)
__device__ __forceinline__ void stage_tab(unsigned short* Wt, const unsigned short* Wb, int tid){
  #pragma unroll
  for(int s = 0; s < 2; s++){
    int c = tid + s*256;           // 512 chunks of 8 elems
    int n = c >> 3, ko = (c & 7)*8;
    *(bf16x8*)&Wt[n*72 + ko] = *(const bf16x8*)&Wb[n*64 + ko];
  }
}

// ---------------- pack weights descriptor ----------------
struct PKS { const float* src; unsigned short* dst; int kshift; int ldw; int col0; };

// ================= PRE: packw(11) | count(1563) | castsum(256) | fold1(1) =================
struct PreP {
  PKS pk[11];
  const int* col; int* cnt;
  const float* x; unsigned short* xb; float* gsum;
  const float* gw1; const float* gas; const float* gad; float* wsd;
};

#define NB_CNT ((NE+255)/256)      // 1563

__global__ __launch_bounds__(256) void k_pre(PreP p){
  __shared__ float part[4][64];
  int b = blockIdx.x, tid = threadIdx.x;
  if(b < 11){
    PKS s = p.pk[b];
    int K = 1 << s.kshift;
    int total = K << 6;
    for(int idx = tid; idx < total; idx += 256){
      int n = idx >> s.kshift, k = idx & (K - 1);
      s.dst[idx] = f2bf(s.src[(size_t)k*s.ldw + s.col0 + n]);
    }
    return;
  }
  if(b < 11 + NB_CNT){
    int e = (b - 11)*256 + tid;
    if(e < NE) atomicAdd(&p.cnt[p.col[e]], 1);
    return;
  }
  if(b < 11 + NB_CNT + 256){
    int lb = b - (11 + NB_CNT);
    int lane = tid & 63, w = tid >> 6;
    float s = 0.f;
    for(int r = lb*4 + w; r < NN; r += 256*4){
      float v = p.x[(size_t)r*64 + lane];
      p.xb[(size_t)r*64 + lane] = f2bf(v);
      s += v;
    }
    part[w][lane] = s;
    __syncthreads();
    if(w == 0) atomicAdd(&p.gsum[lane], part[0][lane]+part[1][lane]+part[2][lane]+part[3][lane]);
    return;
  }
  // fold1
  {
    int k = tid & 63, h = tid >> 6;
    float ssrc = 0.f, sdst = 0.f;
    for(int c = 0; c < 64; c++){
      float w = p.gw1[k*256 + h*64 + c];
      ssrc += w * p.gas[h*64 + c];
      sdst += w * p.gad[h*64 + c];
    }
    p.wsd[k*8 + h] = ssrc;
    p.wsd[k*8 + 4 + h] = sdst;
  }
}

// ---------------- CSR alloc (scan) ----------------
__global__ void k_alloc(const int* __restrict__ cnt, int* __restrict__ offs,
                        float* __restrict__ dis, float* __restrict__ invc,
                        int* __restrict__ total, int N){
  int i = blockIdx.x*blockDim.x + threadIdx.x;
  int lane = threadIdx.x & 63;
  int v = (i < N) ? cnt[i] : 0;
  int x = v;
  #pragma unroll
  for(int d = 1; d < 64; d <<= 1){ int t = __shfl_up(x, d, 64); if(lane >= d) x += t; }
  int base = 0;
  if(lane == 63 && x > 0) base = atomicAdd(total, x);
  base = __shfl(base, 63, 64);
  if(i < N){
    offs[i] = base + x - v;
    dis[i]  = 1.0f / sqrtf((float)(v + 1));
    invc[i] = 1.0f / fmaxf((float)v, 1.0f);
  }
}

// ================= MID: fill(1563) | gate(1) | attdotx(3125) =================
struct MidP {
  const int* row; const int* col; const int* offs; int* cursor; int* csr;
  const float* gsum; const float* w1; const float* b1; const float* w2; const float* b2;
  float* gatew;
  const unsigned short* xb; const float* wsd; float* asrc; float* adst;
};

#define NB_ATT (NN/16)             // 3125

__global__ __launch_bounds__(256) void k_mid(MidP p){
  __shared__ float ws[64*8];
  __shared__ float g[64]; __shared__ float hid[64]; __shared__ float lg[3];
  int b = blockIdx.x, tid = threadIdx.x;
  if(b < NB_CNT){
    int e = b*256 + tid;
    if(e < NE){
      int c = p.col[e];
      int pos = p.offs[c] + atomicAdd(&p.cursor[c], 1);
      p.csr[pos] = p.row[e];
    }
    return;
  }
  if(b == NB_CNT){
    int t = tid;
    if(t < 64) g[t] = p.gsum[t] * (1.0f/(float)NN);
    __syncthreads();
    if(t < 64){
      float acc = p.b1[t];
      for(int i = 0; i < 64; i++) acc += g[i]*p.w1[i*64 + t];
      hid[t] = fmaxf(acc, 0.f);
    }
    __syncthreads();
    if(t < 3){
      float a = p.b2[t];
      for(int j = 0; j < 64; j++) a += hid[j]*p.w2[j*3 + t];
      lg[t] = a;
    }
    __syncthreads();
    if(t == 0){
      float m = fmaxf(lg[0], fmaxf(lg[1], lg[2]));
      float e0 = expf(lg[0]-m), e1 = expf(lg[1]-m), e2 = expf(lg[2]-m);
      float s = e0 + e1 + e2;
      p.gatew[0] = e0/s; p.gatew[1] = e1/s; p.gatew[2] = e2/s;
    }
    return;
  }
  // attdotx
  int lb = b - (NB_CNT + 1);
  ws[tid] = p.wsd[tid];
  ws[tid + 256] = p.wsd[tid + 256];
  __syncthreads();
  int node = lb*16 + (tid >> 4);
  int l = tid & 15;
  if(node >= NN) return;
  uint2 u = *(const uint2*)&p.xb[(size_t)node*64 + l*4];
  float v0 = bflo(u.x), v1 = bfhi(u.x), v2 = bflo(u.y), v3 = bfhi(u.y);
  float s[8];
  #pragma unroll
  for(int h = 0; h < 8; h++){
    s[h] = v0*ws[(l*4+0)*8+h] + v1*ws[(l*4+1)*8+h] + v2*ws[(l*4+2)*8+h] + v3*ws[(l*4+3)*8+h];
  }
  #pragma unroll
  for(int d = 8; d >= 1; d >>= 1){
    #pragma unroll
    for(int h = 0; h < 8; h++) s[h] += __shfl_xor(s[h], d, 16);
  }
  if(l == 0){
    float4 o1; o1.x = s[0]; o1.y = s[1]; o1.z = s[2]; o1.w = s[3];
    float4 o2; o2.x = s[4]; o2.y = s[5]; o2.z = s[6]; o2.w = s[7];
    *(float4*)&p.asrc[node*4] = o1;
    *(float4*)&p.adst[node*4] = o2;
  }
}

// ================= AGG1: layer-1 gather, GAT1 weights inline =================
// 4 edges in flight (16 lanes/edge, 4 channels/lane): halves per-edge VALU share
// of the redundant exp/lrelu vs the old 2-edge (32 lanes/edge) layout.
struct A1P {
  const unsigned short* xb; const float* asrc1; const float* adst1;
  const int* offs; const int* cnt; const int* csr;
  const float* dis; const float* invc;
  unsigned short* z; unsigned short* agcnx; unsigned short* asagex; int N;
};

__global__ void k_agg1(A1P p){
  int node = blockIdx.x*4 + (threadIdx.x >> 6);
  int lane = threadIdx.x & 63;
  if(node >= p.N) return;
  int quad = lane >> 4, sub = lane & 15;    // channels sub*4 .. sub*4+3
  float4 ad4 = *(const float4*)&p.adst1[node*4];
  float zg[4][4] = {{0,0,0,0},{0,0,0,0},{0,0,0,0},{0,0,0,0}};
  float gg[4] = {0,0,0,0}, ssv[4] = {0,0,0,0}, wsum[4] = {0,0,0,0};
  int e0 = p.offs[node], e1 = e0 + p.cnt[node];
  #pragma unroll 2
  for(int e = e0 + quad; e < e1; e += 4){
    int s = p.csr[e];
    float4 as4 = *(const float4*)&p.asrc1[s*4];
    float ds = p.dis[s];
    uint2 u = *(const uint2*)&p.xb[(size_t)s*64 + sub*4];
    float w0 = fexp(lrelu(as4.x + ad4.x));
    float w1 = fexp(lrelu(as4.y + ad4.y));
    float w2 = fexp(lrelu(as4.z + ad4.z));
    float w3 = fexp(lrelu(as4.w + ad4.w));
    float x0 = bflo(u.x), x1 = bfhi(u.x), x2 = bflo(u.y), x3 = bfhi(u.y);
    zg[0][0] = fmaf(w0, x0, zg[0][0]); zg[0][1] = fmaf(w0, x1, zg[0][1]);
    zg[0][2] = fmaf(w0, x2, zg[0][2]); zg[0][3] = fmaf(w0, x3, zg[0][3]);
    zg[1][0] = fmaf(w1, x0, zg[1][0]); zg[1][1] = fmaf(w1, x1, zg[1][1]);
    zg[1][2] = fmaf(w1, x2, zg[1][2]); zg[1][3] = fmaf(w1, x3, zg[1][3]);
    zg[2][0] = fmaf(w2, x0, zg[2][0]); zg[2][1] = fmaf(w2, x1, zg[2][1]);
    zg[2][2] = fmaf(w2, x2, zg[2][2]); zg[2][3] = fmaf(w2, x3, zg[2][3]);
    zg[3][0] = fmaf(w3, x0, zg[3][0]); zg[3][1] = fmaf(w3, x1, zg[3][1]);
    zg[3][2] = fmaf(w3, x2, zg[3][2]); zg[3][3] = fmaf(w3, x3, zg[3][3]);
    gg[0] = fmaf(ds, x0, gg[0]); gg[1] = fmaf(ds, x1, gg[1]);
    gg[2] = fmaf(ds, x2, gg[2]); gg[3] = fmaf(ds, x3, gg[3]);
    ssv[0] += x0; ssv[1] += x1; ssv[2] += x2; ssv[3] += x3;
    wsum[0] += w0; wsum[1] += w1; wsum[2] += w2; wsum[3] += w3;
  }
  // reduce across the 4 quads (xor 16 then 32)
  #pragma unroll
  for(int h = 0; h < 4; h++){
    #pragma unroll
    for(int c = 0; c < 4; c++){
      zg[h][c] += __shfl_xor(zg[h][c], 16, 64);
      zg[h][c] += __shfl_xor(zg[h][c], 32, 64);
    }
    wsum[h] += __shfl_xor(wsum[h], 16, 64);
    wsum[h] += __shfl_xor(wsum[h], 32, 64);
  }
  #pragma unroll
  for(int c = 0; c < 4; c++){
    gg[c]  += __shfl_xor(gg[c], 16, 64);  gg[c]  += __shfl_xor(gg[c], 32, 64);
    ssv[c] += __shfl_xor(ssv[c], 16, 64); ssv[c] += __shfl_xor(ssv[c], 32, 64);
  }
  if(quad == 0){
    uint2 un = *(const uint2*)&p.xb[(size_t)node*64 + sub*4];
    float x0 = bflo(un.x), x1 = bfhi(un.x), x2 = bflo(un.y), x3 = bfhi(un.y);
    float4 asn = *(const float4*)&p.asrc1[node*4];
    float s0 = fexp(lrelu(asn.x + ad4.x));
    float s1 = fexp(lrelu(asn.y + ad4.y));
    float s2 = fexp(lrelu(asn.z + ad4.z));
    float s3 = fexp(lrelu(asn.w + ad4.w));
    float rd0 = 1.0f/(wsum[0] + s0), rd1 = 1.0f/(wsum[1] + s1);
    float rd2 = 1.0f/(wsum[2] + s2), rd3 = 1.0f/(wsum[3] + s3);
    {
      uint2 o;
      o.x = pack2((zg[0][0] + s0*x0)*rd0, (zg[0][1] + s0*x1)*rd0);
      o.y = pack2((zg[0][2] + s0*x2)*rd0, (zg[0][3] + s0*x3)*rd0);
      *(uint2*)&p.z[(size_t)node*256 + 0*64 + sub*4] = o;
      o.x = pack2((zg[1][0] + s1*x0)*rd1, (zg[1][1] + s1*x1)*rd1);
      o.y = pack2((zg[1][2] + s1*x2)*rd1, (zg[1][3] + s1*x3)*rd1);
      *(uint2*)&p.z[(size_t)node*256 + 1*64 + sub*4] = o;
      o.x = pack2((zg[2][0] + s2*x0)*rd2, (zg[2][1] + s2*x1)*rd2);
      o.y = pack2((zg[2][2] + s2*x2)*rd2, (zg[2][3] + s2*x3)*rd2);
      *(uint2*)&p.z[(size_t)node*256 + 2*64 + sub*4] = o;
      o.x = pack2((zg[3][0] + s3*x0)*rd3, (zg[3][1] + s3*x1)*rd3);
      o.y = pack2((zg[3][2] + s3*x2)*rd3, (zg[3][3] + s3*x3)*rd3);
      *(uint2*)&p.z[(size_t)node*256 + 3*64 + sub*4] = o;
    }
    float dc = p.dis[node], ic = p.invc[node];
    uint2 og;
    og.x = pack2(dc*fmaf(dc, x0, gg[0]), dc*fmaf(dc, x1, gg[1]));
    og.y = pack2(dc*fmaf(dc, x2, gg[2]), dc*fmaf(dc, x3, gg[3]));
    *(uint2*)&p.agcnx[(size_t)node*64 + sub*4] = og;
    uint2 os;
    os.x = pack2(ssv[0]*ic, ssv[1]*ic);
    os.y = pack2(ssv[2]*ic, ssv[3]*ic);
    *(uint2*)&p.asagex[(size_t)node*64 + sub*4] = os;
  }
}

// ================= AGG2: layer-2 gather, GAT2 weights inline (4 edges in flight) =================
struct A2P {
  const unsigned short* a1; const unsigned short* s1; const unsigned short* h2;
  const float* asrc2; const float* adst2;
  const int* offs; const int* cnt; const int* csr;
  const float* dis; const float* invc;
  unsigned short* A2agg; unsigned short* S2agg; unsigned short* T2; int N;
};

__global__ void k_agg2(A2P p){
  int node = blockIdx.x*4 + (threadIdx.x >> 6);
  int lane = threadIdx.x & 63;
  if(node >= p.N) return;
  int quad = lane >> 4, sub = lane & 15;
  float ad = p.adst2[node];
  float aa[4] = {0,0,0,0}, ss[4] = {0,0,0,0}, tt[4] = {0,0,0,0}, wsum = 0.f;
  int e0 = p.offs[node], e1 = e0 + p.cnt[node];
  #pragma unroll 2
  for(int e = e0 + quad; e < e1; e += 4){
    int s = p.csr[e];
    float wv = fexp(lrelu(p.asrc2[s] + ad));
    float ds = p.dis[s];
    uint2 ua = *(const uint2*)&p.a1[(size_t)s*64 + sub*4];
    uint2 us = *(const uint2*)&p.s1[(size_t)s*64 + sub*4];
    uint2 uh = *(const uint2*)&p.h2[(size_t)s*64 + sub*4];
    aa[0] = fmaf(ds, bflo(ua.x), aa[0]); aa[1] = fmaf(ds, bfhi(ua.x), aa[1]);
    aa[2] = fmaf(ds, bflo(ua.y), aa[2]); aa[3] = fmaf(ds, bfhi(ua.y), aa[3]);
    ss[0] += bflo(us.x); ss[1] += bfhi(us.x);
    ss[2] += bflo(us.y); ss[3] += bfhi(us.y);
    tt[0] = fmaf(wv, bflo(uh.x), tt[0]); tt[1] = fmaf(wv, bfhi(uh.x), tt[1]);
    tt[2] = fmaf(wv, bflo(uh.y), tt[2]); tt[3] = fmaf(wv, bfhi(uh.y), tt[3]);
    wsum += wv;
  }
  #pragma unroll
  for(int c = 0; c < 4; c++){
    aa[c] += __shfl_xor(aa[c], 16, 64); aa[c] += __shfl_xor(aa[c], 32, 64);
    ss[c] += __shfl_xor(ss[c], 16, 64); ss[c] += __shfl_xor(ss[c], 32, 64);
    tt[c] += __shfl_xor(tt[c], 16, 64); tt[c] += __shfl_xor(tt[c], 32, 64);
  }
  wsum += __shfl_xor(wsum, 16, 64);
  wsum += __shfl_xor(wsum, 32, 64);
  if(quad == 0){
    float wss = fexp(lrelu(p.asrc2[node] + ad));
    float rd = 1.0f/(wsum + wss);
    uint2 uan = *(const uint2*)&p.a1[(size_t)node*64 + sub*4];
    uint2 uhn = *(const uint2*)&p.h2[(size_t)node*64 + sub*4];
    float dc = p.dis[node], ic = p.invc[node];
    uint2 oa;
    oa.x = pack2(dc*fmaf(dc, bflo(uan.x), aa[0]), dc*fmaf(dc, bfhi(uan.x), aa[1]));
    oa.y = pack2(dc*fmaf(dc, bflo(uan.y), aa[2]), dc*fmaf(dc, bfhi(uan.y), aa[3]));
    *(uint2*)&p.A2agg[(size_t)node*64 + sub*4] = oa;
    uint2 os;
    os.x = pack2(ss[0]*ic, ss[1]*ic);
    os.y = pack2(ss[2]*ic, ss[3]*ic);
    *(uint2*)&p.S2agg[(size_t)node*64 + sub*4] = os;
    uint2 ot;
    ot.x = pack2(fmaf(wss, bflo(uhn.x), tt[0])*rd, fmaf(wss, bfhi(uhn.x), tt[1])*rd);
    ot.y = pack2(fmaf(wss, bflo(uhn.y), tt[2])*rd, fmaf(wss, bfhi(uhn.y), tt[3])*rd);
    *(uint2*)&p.T2[(size_t)node*64 + sub*4] = ot;
  }
}

// ---------------- fused dispatch: y=0 GAT1+2, y=1 GCN1 mm, y=2 SAGE1 mm ----------------
struct MME {
  const unsigned short* A; const unsigned short* Wb;
  const unsigned short* A2; const unsigned short* Wb2;  // optional second segment (K2=64)
  unsigned short* C;
  const float* b; const float* p1; const float* p2;
  int ep;                                               // 1 = BN+relu; 3 = sage
};
struct FSP {
  const unsigned short* z; const unsigned short* wb1; const float* b1;
  const unsigned short* wb2; const float* as2; const float* ad2;
  unsigned short* h2; float* asrc2; float* adst2;
  MME mm[2];
  int N;
};

__global__ __launch_bounds__(256, 4) void k_fused1(FSP p){
  __shared__ unsigned short smem[64*GHP];  // GAT: GH[64][GHP]; mm: 2x [64][72] tables
  const int N = p.N;
  int tid = threadIdx.x;
  int w = tid >> 6, lane = tid & 63, quad = lane >> 4, m16 = lane & 15;
  int rowa = blockIdx.x*64 + w*16 + m16;
  int rowc = rowa < N ? rowa : N - 1;
  int robase = blockIdx.x*64 + w*16 + quad*4;

  if(blockIdx.y == 0){
    // ================= GAT layer1+layer2, one barrier =================
    unsigned short* GH = smem;             // pitch GHP (264 >= 256 row payload)
    int lr = w*16;
    #pragma unroll
    for(int h = 0; h < 4; h++){
      bf16x8 a0 = *(const bf16x8*)&p.z[(size_t)rowc*256 + h*64 + quad*8];
      bf16x8 a1 = *(const bf16x8*)&p.z[(size_t)rowc*256 + h*64 + 32 + quad*8];
      f32x4 acc[4];
      #pragma unroll
      for(int t = 0; t < 4; t++){ acc[t][0]=0.f; acc[t][1]=0.f; acc[t][2]=0.f; acc[t][3]=0.f; }
      #pragma unroll
      for(int t = 0; t < 4; t++){
        const unsigned short* wb = p.wb1 + (size_t)h*4096 + (t*16 + m16)*64;
        bf16x8 b0 = *(const bf16x8*)&wb[quad*8];
        bf16x8 b1v = *(const bf16x8*)&wb[32 + quad*8];
        acc[t] = __builtin_amdgcn_mfma_f32_16x16x32_bf16(a0, b0, acc[t], 0, 0, 0);
        acc[t] = __builtin_amdgcn_mfma_f32_16x16x32_bf16(a1, b1v, acc[t], 0, 0, 0);
      }
      #pragma unroll
      for(int t = 0; t < 4; t++){
        float bv = p.b1[h*64 + t*16 + m16];
        #pragma unroll
        for(int r = 0; r < 4; r++){
          GH[(lr + quad*4 + r)*GHP + h*64 + t*16 + m16] = f2bf(elu1(acc[t][r] + bv));
        }
      }
    }
    __syncthreads();
    f32x4 acc2[4];
    #pragma unroll
    for(int t = 0; t < 4; t++){ acc2[t][0]=0.f; acc2[t][1]=0.f; acc2[t][2]=0.f; acc2[t][3]=0.f; }
    #pragma unroll
    for(int kc = 0; kc < 256; kc += 64){
      bf16x8 a0 = *(const bf16x8*)&GH[(lr + m16)*GHP + kc + quad*8];
      bf16x8 a1 = *(const bf16x8*)&GH[(lr + m16)*GHP + kc + 32 + quad*8];
      #pragma unroll
      for(int t = 0; t < 4; t++){
        const unsigned short* wb = p.wb2 + (size_t)(t*16 + m16)*256 + kc;
        bf16x8 b0 = *(const bf16x8*)&wb[quad*8];
        bf16x8 b1v = *(const bf16x8*)&wb[32 + quad*8];
        acc2[t] = __builtin_amdgcn_mfma_f32_16x16x32_bf16(a0, b0, acc2[t], 0, 0, 0);
        acc2[t] = __builtin_amdgcn_mfma_f32_16x16x32_bf16(a1, b1v, acc2[t], 0, 0, 0);
      }
    }
    #pragma unroll
    for(int t = 0; t < 4; t++){
      int col = t*16 + m16;
      #pragma unroll
      for(int r = 0; r < 4; r++){
        int ro = robase + r;
        if(ro < N) p.h2[(size_t)ro*64 + col] = f2bf(acc2[t][r]);
      }
    }
    float ps[4] = {0,0,0,0}, pd[4] = {0,0,0,0};
    #pragma unroll
    for(int t = 0; t < 4; t++){
      int col = t*16 + m16;
      float a_ = p.as2[col], d_ = p.ad2[col];
      #pragma unroll
      for(int r = 0; r < 4; r++){ ps[r] = fmaf(acc2[t][r], a_, ps[r]); pd[r] = fmaf(acc2[t][r], d_, pd[r]); }
    }
    #pragma unroll
    for(int d = 8; d >= 1; d >>= 1){
      #pragma unroll
      for(int r = 0; r < 4; r++){ ps[r] += __shfl_xor(ps[r], d, 64); pd[r] += __shfl_xor(pd[r], d, 64); }
    }
    if(m16 == 0){
      #pragma unroll
      for(int r = 0; r < 4; r++){
        int ro = robase + r;
        if(ro < N){ p.asrc2[ro] = ps[r]; p.adst2[ro] = pd[r]; }
      }
    }
    return;
  }

  // ================= GCN / SAGE layer-1 matmuls (LDS-staged B) =================
  MME m = p.mm[blockIdx.y - 1];
  unsigned short* Wt  = smem;
  unsigned short* Wt2 = smem + 4608;
  stage_tab(Wt, m.Wb, tid);
  if(m.Wb2) stage_tab(Wt2, m.Wb2, tid);
  __syncthreads();
  f32x4 acc[4];
  #pragma unroll
  for(int t = 0; t < 4; t++){ acc[t][0]=0.f; acc[t][1]=0.f; acc[t][2]=0.f; acc[t][3]=0.f; }
  {
    bf16x8 a0 = *(const bf16x8*)&m.A[(size_t)rowc*64 + quad*8];
    bf16x8 a1 = *(const bf16x8*)&m.A[(size_t)rowc*64 + 32 + quad*8];
    #pragma unroll
    for(int t = 0; t < 4; t++){
      bf16x8 b0 = *(const bf16x8*)&Wt[(t*16 + m16)*72 + quad*8];
      bf16x8 b1 = *(const bf16x8*)&Wt[(t*16 + m16)*72 + 32 + quad*8];
      acc[t] = __builtin_amdgcn_mfma_f32_16x16x32_bf16(a0, b0, acc[t], 0, 0, 0);
      acc[t] = __builtin_amdgcn_mfma_f32_16x16x32_bf16(a1, b1, acc[t], 0, 0, 0);
    }
  }
  if(m.A2){
    bf16x8 a0 = *(const bf16x8*)&m.A2[(size_t)rowc*64 + quad*8];
    bf16x8 a1 = *(const bf16x8*)&m.A2[(size_t)rowc*64 + 32 + quad*8];
    #pragma unroll
    for(int t = 0; t < 4; t++){
      bf16x8 b0 = *(const bf16x8*)&Wt2[(t*16 + m16)*72 + quad*8];
      bf16x8 b1 = *(const bf16x8*)&Wt2[(t*16 + m16)*72 + 32 + quad*8];
      acc[t] = __builtin_amdgcn_mfma_f32_16x16x32_bf16(a0, b0, acc[t], 0, 0, 0);
      acc[t] = __builtin_amdgcn_mfma_f32_16x16x32_bf16(a1, b1, acc[t], 0, 0, 0);
    }
  }
  if(m.ep == 3){
    float v[4][4], n2[4] = {0,0,0,0};
    #pragma unroll
    for(int t = 0; t < 4; t++){
      float bv = m.b[t*16 + m16];
      #pragma unroll
      for(int r = 0; r < 4; r++){ v[t][r] = acc[t][r] + bv; n2[r] = fmaf(v[t][r], v[t][r], n2[r]); }
    }
    #pragma unroll
    for(int d = 8; d >= 1; d >>= 1){
      #pragma unroll
      for(int r = 0; r < 4; r++) n2[r] += __shfl_xor(n2[r], d, 64);
    }
    float inv[4];
    #pragma unroll
    for(int r = 0; r < 4; r++) inv[r] = 1.0f / fmaxf(sqrtf(n2[r]), 1e-12f);
    #pragma unroll
    for(int t = 0; t < 4; t++){
      #pragma unroll
      for(int r = 0; r < 4; r++){
        int ro = robase + r;
        if(ro < N) m.C[(size_t)ro*64 + t*16 + m16] = f2bf(fmaxf(v[t][r]*inv[r], 0.f));
      }
    }
    return;
  }
  // ep == 1: BN + relu
  #pragma unroll
  for(int t = 0; t < 4; t++){
    int col = t*16 + m16;
    float bv = m.b[col];
    float gm = m.p1[col]*rsqrtf(1.0f + 1e-5f);
    float be = m.p2[col];
    #pragma unroll
    for(int r = 0; r < 4; r++){
      int ro = robase + r;
      if(ro < N){
        m.C[(size_t)ro*64 + col] = f2bf(fmaxf((acc[t][r] + bv)*gm + be, 0.f));
      }
    }
  }
}

// ---------------- final: GCN2 mm + SAGE2 dual mm + L2norm + GAT2 add + gate combine ----------------
__global__ __launch_bounds__(256) void k_mm_final(
    const unsigned short* __restrict__ A2agg, const unsigned short* __restrict__ wb_gcn2,
    const float* __restrict__ gcn_b2,
    const unsigned short* __restrict__ S2agg, const unsigned short* __restrict__ wb_wl2,
    const float* __restrict__ bl2,
    const unsigned short* __restrict__ s1, const unsigned short* __restrict__ wb_wr2,
    const unsigned short* __restrict__ T2, const float* __restrict__ gat_b2,
    const float* __restrict__ gatew, float* __restrict__ out, int N){
  __shared__ unsigned short W1s[64*72];
  __shared__ unsigned short W2s[64*72];
  __shared__ unsigned short W3s[64*72];
  int tid = threadIdx.x;
  stage_tab(W1s, wb_gcn2, tid);
  stage_tab(W2s, wb_wl2, tid);
  stage_tab(W3s, wb_wr2, tid);
  __syncthreads();
  int w = tid >> 6, lane = tid & 63, quad = lane >> 4, m16 = lane & 15;
  int rowa = blockIdx.x*64 + w*16 + m16;
  int rowc = rowa < N ? rowa : N - 1;
  f32x4 accg[4], accs[4];
  #pragma unroll
  for(int t = 0; t < 4; t++){
    accg[t][0]=0.f; accg[t][1]=0.f; accg[t][2]=0.f; accg[t][3]=0.f;
    accs[t][0]=0.f; accs[t][1]=0.f; accs[t][2]=0.f; accs[t][3]=0.f;
  }
  {
    bf16x8 a0 = *(const bf16x8*)&A2agg[(size_t)rowc*64 + quad*8];
    bf16x8 a1 = *(const bf16x8*)&A2agg[(size_t)rowc*64 + 32 + quad*8];
    #pragma unroll
    for(int t = 0; t < 4; t++){
      bf16x8 b0 = *(const bf16x8*)&W1s[(t*16 + m16)*72 + quad*8];
      bf16x8 b1 = *(const bf16x8*)&W1s[(t*16 + m16)*72 + 32 + quad*8];
      accg[t] = __builtin_amdgcn_mfma_f32_16x16x32_bf16(a0, b0, accg[t], 0, 0, 0);
      accg[t] = __builtin_amdgcn_mfma_f32_16x16x32_bf16(a1, b1, accg[t], 0, 0, 0);
    }
  }
  {
    bf16x8 a0 = *(const bf16x8*)&S2agg[(size_t)rowc*64 + quad*8];
    bf16x8 a1 = *(const bf16x8*)&S2agg[(size_t)rowc*64 + 32 + quad*8];
    #pragma unroll
    for(int t = 0; t < 4; t++){
      bf16x8 b0 = *(const bf16x8*)&W2s[(t*16 + m16)*72 + quad*8];
      bf16x8 b1 = *(const bf16x8*)&W2s[(t*16 + m16)*72 + 32 + quad*8];
      accs[t] = __builtin_amdgcn_mfma_f32_16x16x32_bf16(a0, b0, accs[t], 0, 0, 0);
      accs[t] = __builtin_amdgcn_mfma_f32_16x16x32_bf16(a1, b1, accs[t], 0, 0, 0);
    }
  }
  {
    bf16x8 a0 = *(const bf16x8*)&s1[(size_t)rowc*64 + quad*8];
    bf16x8 a1 = *(const bf16x8*)&s1[(size_t)rowc*64 + 32 + quad*8];
    #pragma unroll
    for(int t = 0; t < 4; t++){
      bf16x8 b0 = *(const bf16x8*)&W3s[(t*16 + m16)*72 + quad*8];
      bf16x8 b1 = *(const bf16x8*)&W3s[(t*16 + m16)*72 + 32 + quad*8];
      accs[t] = __builtin_amdgcn_mfma_f32_16x16x32_bf16(a0, b0, accs[t], 0, 0, 0);
      accs[t] = __builtin_amdgcn_mfma_f32_16x16x32_bf16(a1, b1, accs[t], 0, 0, 0);
    }
  }
  float w0 = gatew[0], w1 = gatew[1], w2 = gatew[2];
  int robase = blockIdx.x*64 + w*16 + quad*4;
  float vs[4][4], n2[4] = {0,0,0,0};
  #pragma unroll
  for(int t = 0; t < 4; t++){
    float bsv = bl2[t*16 + m16];
    #pragma unroll
    for(int r = 0; r < 4; r++){ vs[t][r] = accs[t][r] + bsv; n2[r] = fmaf(vs[t][r], vs[t][r], n2[r]); }
  }
  #pragma unroll
  for(int d = 8; d >= 1; d >>= 1){
    #pragma unroll
    for(int r = 0; r < 4; r++) n2[r] += __shfl_xor(n2[r], d, 64);
  }
  float inv[4];
  #pragma unroll
  for(int r = 0; r < 4; r++) inv[r] = 1.0f / fmaxf(sqrtf(n2[r]), 1e-12f);
  #pragma unroll
  for(int t = 0; t < 4; t++){
    int col = t*16 + m16;
    float bg = gcn_b2[col], bt = gat_b2[col];
    #pragma unroll
    for(int r = 0; r < 4; r++){
      int ro = robase + r;
      if(ro < N){
        float t2 = bflo((unsigned int)T2[(size_t)ro*64 + col]);
        out[(size_t)ro*64 + col] = w0*(accg[t][r] + bg) + w1*(t2 + bt) + w2*vs[t][r]*inv[r];
      }
    }
  }
}

// ---------------- host ----------------
extern "C" void kernel_launch(void* const* d_in, const int* in_sizes, int n_in,
                              void* d_out, int out_size, void* d_ws, size_t ws_size,
                              hipStream_t stream){
  const float* x        = (const float*)d_in[0];
  const int*   ei       = (const int*)d_in[1];
  const int*   row      = ei;
  const int*   col      = ei + NE;
  const float* gate_w1  = (const float*)d_in[2];
  const float* gate_b1  = (const float*)d_in[3];
  const float* gate_w2  = (const float*)d_in[4];
  const float* gate_b2  = (const float*)d_in[5];
  const float* gcn_w1   = (const float*)d_in[6];
  const float* gcn_b1   = (const float*)d_in[7];
  const float* bn_gamma = (const float*)d_in[8];
  const float* bn_beta  = (const float*)d_in[9];
  const float* gcn_w2   = (const float*)d_in[10];
  const float* gcn_b2   = (const float*)d_in[11];
  const float* gat_w1   = (const float*)d_in[12];
  const float* gat_as1  = (const float*)d_in[13];
  const float* gat_ad1  = (const float*)d_in[14];
  const float* gat_b1   = (const float*)d_in[15];
  const float* gat_w2   = (const float*)d_in[16];
  const float* gat_as2  = (const float*)d_in[17];
  const float* gat_ad2  = (const float*)d_in[18];
  const float* gat_b2   = (const float*)d_in[19];
  const float* sage_wl1 = (const float*)d_in[20];
  const float* sage_bl1 = (const float*)d_in[21];
  const float* sage_wr1 = (const float*)d_in[22];
  const float* sage_wl2 = (const float*)d_in[23];
  const float* sage_bl2 = (const float*)d_in[24];
  const float* sage_wr2 = (const float*)d_in[25];
  float* out = (float*)d_out;

  char* wp = (char*)d_ws;
  auto alloc = [&](size_t bytes)->char*{ char* p = wp; wp += (bytes + 255) & ~(size_t)255; return p; };
  // zero-init region (contiguous): cnt, cursor, gsum, total
  int*   cnt    = (int*)  alloc((size_t)NN*4);
  int*   cursor = (int*)  alloc((size_t)NN*4);
  float* gsum   = (float*)alloc(64*4);
  int*   total  = (int*)  alloc(256);
  size_t zbytes = (size_t)(wp - (char*)cnt);
  int*   offs   = (int*)  alloc((size_t)NN*4);
  int*   csr    = (int*)  alloc((size_t)NE*4);
  float* dis    = (float*)alloc((size_t)NN*4);
  float* invc   = (float*)alloc((size_t)NN*4);
  float* gatew  = (float*)alloc(16);
  float* wsd    = (float*)alloc(64*8*4);
  float* asrc1  = (float*)alloc((size_t)NN*4*4);
  float* adst1  = (float*)alloc((size_t)NN*4*4);
  float* asrc2  = (float*)alloc((size_t)NN*4);
  float* adst2  = (float*)alloc((size_t)NN*4);
  unsigned short* xb     = (unsigned short*)alloc((size_t)NN*64*2);
  unsigned short* z      = (unsigned short*)alloc((size_t)NN*256*2);
  unsigned short* agcnx  = (unsigned short*)alloc((size_t)NN*64*2);
  unsigned short* asagex = (unsigned short*)alloc((size_t)NN*64*2);
  unsigned short* a1     = (unsigned short*)alloc((size_t)NN*64*2);
  unsigned short* s1     = (unsigned short*)alloc((size_t)NN*64*2);
  unsigned short* h2     = (unsigned short*)alloc((size_t)NN*64*2);
  unsigned short* A2agg  = (unsigned short*)alloc((size_t)NN*64*2);
  unsigned short* S2agg  = (unsigned short*)alloc((size_t)NN*64*2);
  unsigned short* T2     = (unsigned short*)alloc((size_t)NN*64*2);
  // packed bf16 weights (B-operand layout [n][K])
  unsigned short* wb_gcn1 = (unsigned short*)alloc((size_t)64*64*2);
  unsigned short* wb_wl1  = (unsigned short*)alloc((size_t)64*64*2);
  unsigned short* wb_wr1  = (unsigned short*)alloc((size_t)64*64*2);
  unsigned short* wb_gat1 = (unsigned short*)alloc((size_t)256*64*2);
  unsigned short* wb_gat2 = (unsigned short*)alloc((size_t)64*256*2);
  unsigned short* wb_gcn2 = (unsigned short*)alloc((size_t)64*64*2);
  unsigned short* wb_wl2  = (unsigned short*)alloc((size_t)64*64*2);
  unsigned short* wb_wr2  = (unsigned short*)alloc((size_t)64*64*2);

  hipMemsetAsync(cnt, 0, zbytes, stream);

  const int gN  = (NN + 63) / 64;   // 782
  const int g4  = NN / 4;           // 12500
  const int gA  = (NN + 255) / 256; // 196

  // ---- pre: packw | count | castsum | fold1 ----
  {
    PreP p = {};
    p.pk[0]  = {gcn_w1,   wb_gcn1,            6, 64,  0};
    p.pk[1]  = {sage_wl1, wb_wl1,             6, 64,  0};
    p.pk[2]  = {sage_wr1, wb_wr1,             6, 64,  0};
    p.pk[3]  = {gat_w1,   wb_gat1 + 0*64*64,  6, 256, 0};
    p.pk[4]  = {gat_w1,   wb_gat1 + 1*64*64,  6, 256, 64};
    p.pk[5]  = {gat_w1,   wb_gat1 + 2*64*64,  6, 256, 128};
    p.pk[6]  = {gat_w1,   wb_gat1 + 3*64*64,  6, 256, 192};
    p.pk[7]  = {gat_w2,   wb_gat2,            8, 64,  0};
    p.pk[8]  = {gcn_w2,   wb_gcn2,            6, 64,  0};
    p.pk[9]  = {sage_wl2, wb_wl2,             6, 64,  0};
    p.pk[10] = {sage_wr2, wb_wr2,             6, 64,  0};
    p.col = col; p.cnt = cnt;
    p.x = x; p.xb = xb; p.gsum = gsum;
    p.gw1 = gat_w1; p.gas = gat_as1; p.gad = gat_ad1; p.wsd = wsd;
    k_pre<<<11 + NB_CNT + 256 + 1, 256, 0, stream>>>(p);
  }

  k_alloc<<<gA, 256, 0, stream>>>(cnt, offs, dis, invc, total, NN);

  // ---- mid: fill | gate | attdotx ----
  {
    MidP p = {};
    p.row = row; p.col = col; p.offs = offs; p.cursor = cursor; p.csr = csr;
    p.gsum = gsum; p.w1 = gate_w1; p.b1 = gate_b1; p.w2 = gate_w2; p.b2 = gate_b2;
    p.gatew = gatew;
    p.xb = xb; p.wsd = wsd; p.asrc = asrc1; p.adst = adst1;
    k_mid<<<NB_CNT + 1 + NB_ATT, 256, 0, stream>>>(p);
  }

  // ---- layer-1 gather with inline GAT1 edge weights (4 edges/wave) ----
  {
    A1P p = {};
    p.xb = xb; p.asrc1 = asrc1; p.adst1 = adst1;
    p.offs = offs; p.cnt = cnt; p.csr = csr; p.dis = dis; p.invc = invc;
    p.z = z; p.agcnx = agcnx; p.asagex = asagex; p.N = NN;
    k_agg1<<<g4, 256, 0, stream>>>(p);
  }

  // ---- fused: GAT1+GAT2 (y=0), GCN1 mm (y=1), SAGE1 mm (y=2) ----
  {
    FSP p = {};
    p.N = NN;
    p.z = z; p.wb1 = wb_gat1; p.b1 = gat_b1;
    p.wb2 = wb_gat2; p.as2 = gat_as2; p.ad2 = gat_ad2;
    p.h2 = h2; p.asrc2 = asrc2; p.adst2 = adst2;
    p.mm[0] = {agcnx, wb_gcn1, nullptr, nullptr, a1, gcn_b1, bn_gamma, bn_beta, 1};
    p.mm[1] = {asagex, wb_wl1, xb, wb_wr1, s1, sage_bl1, nullptr, nullptr, 3};
    k_fused1<<<dim3(gN,3), 256, 0, stream>>>(p);
  }

  // ---- layer-2 gather with inline GAT2 edge weights (4 edges/wave) ----
  {
    A2P p = {};
    p.a1 = a1; p.s1 = s1; p.h2 = h2; p.asrc2 = asrc2; p.adst2 = adst2;
    p.offs = offs; p.cnt = cnt; p.csr = csr; p.dis = dis; p.invc = invc;
    p.A2agg = A2agg; p.S2agg = S2agg; p.T2 = T2; p.N = NN;
    k_agg2<<<g4, 256, 0, stream>>>(p);
  }

  // ---- final matmuls + gate combine ----
  k_mm_final<<<gN, 256, 0, stream>>>(A2agg, wb_gcn2, gcn_b2, S2agg, wb_wl2, sage_bl2,
                                     s1, wb_wr2, T2, gat_b2, gatew, out, NN);
}

// Round 11
// 308.070 us; speedup vs baseline: 1.0068x; 1.0066x over previous
//
#include <hip/hip_runtime.h>
#include <hip/hip_bf16.h>
#include <math.h>

#define NN 50000
#define NE 400000

typedef __attribute__((ext_vector_type(8))) short bf16x8;
typedef __attribute__((ext_vector_type(4))) float f32x4;

// GH LDS pitch: row payload is 256 elems (4 heads x 64); min 16B-aligned pitch > 256 is 264.
// (Round-6 lesson: pitch 248 < row width 256 => row overlap, silent corruption.)
#define GHP 264

// ---------------- helpers ----------------
__device__ __forceinline__ float lrelu(float v){ return v > 0.f ? v : 0.2f*v; }
// fast ELU: v>0 ? v : exp(v)-1 via HW v_exp; abs err ~6e-8, far below bf16 quantum
__device__ __forceinline__ float elu1(float v){ return v > 0.f ? v : __expf(v) - 1.0f; }
// fast hardware exp: v_mul (log2e) + v_exp_f32; rel err ~1e-7
__device__ __forceinline__ float fexp(float v){ return __expf(v); }
__device__ __forceinline__ float bflo(unsigned int u){ return __uint_as_float(u << 16); }
__device__ __forceinline__ float bfhi(unsigned int u){ return __uint_as_float(u & 0xffff0000u); }
__device__ __forceinline__ unsigned short f2bf(float f){
  __hip_bfloat16 h = __float2bfloat16(f);
  return *(unsigned short*)&h;
}
__device__ __forceinline__ unsigned int pack2(float lo, float hi){
  return (unsigned int)f2bf(lo) | ((unsigned int)f2bf(hi) << 16);
}

// stage a packed bf16 [64][64] table into LDS with pitch 72 (2-way-free reads)
__device__ __forceinline__ void stage_tab(unsigned short* Wt, const unsigned short* Wb, int tid){
  #pragma unroll
  for(int s = 0; s < 2; s++){
    int c = tid + s*256;           // 512 chunks of 8 elems
    int n = c >> 3, ko = (c & 7)*8;
    *(bf16x8*)&Wt[n*72 + ko] = *(const bf16x8*)&Wb[n*64 + ko];
  }
}

// ---------------- pack weights descriptor ----------------
struct PKS { const float* src; unsigned short* dst; int kshift; int ldw; int col0; };

// ================= PRE: packw(11) | count(1563) | castsum(256) | fold1(1) =================
struct PreP {
  PKS pk[11];
  const int* col; int* cnt;
  const float* x; unsigned short* xb; float* gsum;
  const float* gw1; const float* gas; const float* gad; float* wsd;
};

#define NB_CNT ((NE+255)/256)      // 1563

__global__ __launch_bounds__(256) void k_pre(PreP p){
  __shared__ float part[4][64];
  int b = blockIdx.x, tid = threadIdx.x;
  if(b < 11){
    PKS s = p.pk[b];
    int K = 1 << s.kshift;
    int total = K << 6;
    for(int idx = tid; idx < total; idx += 256){
      int n = idx >> s.kshift, k = idx & (K - 1);
      s.dst[idx] = f2bf(s.src[(size_t)k*s.ldw + s.col0 + n]);
    }
    return;
  }
  if(b < 11 + NB_CNT){
    int e = (b - 11)*256 + tid;
    if(e < NE) atomicAdd(&p.cnt[p.col[e]], 1);
    return;
  }
  if(b < 11 + NB_CNT + 256){
    int lb = b - (11 + NB_CNT);
    int lane = tid & 63, w = tid >> 6;
    float s = 0.f;
    for(int r = lb*4 + w; r < NN; r += 256*4){
      float v = p.x[(size_t)r*64 + lane];
      p.xb[(size_t)r*64 + lane] = f2bf(v);
      s += v;
    }
    part[w][lane] = s;
    __syncthreads();
    if(w == 0) atomicAdd(&p.gsum[lane], part[0][lane]+part[1][lane]+part[2][lane]+part[3][lane]);
    return;
  }
  // fold1
  {
    int k = tid & 63, h = tid >> 6;
    float ssrc = 0.f, sdst = 0.f;
    for(int c = 0; c < 64; c++){
      float w = p.gw1[k*256 + h*64 + c];
      ssrc += w * p.gas[h*64 + c];
      sdst += w * p.gad[h*64 + c];
    }
    p.wsd[k*8 + h] = ssrc;
    p.wsd[k*8 + 4 + h] = sdst;
  }
}

// ---------------- CSR alloc (scan) ----------------
__global__ void k_alloc(const int* __restrict__ cnt, int* __restrict__ offs,
                        float* __restrict__ dis, float* __restrict__ invc,
                        int* __restrict__ total, int N){
  int i = blockIdx.x*blockDim.x + threadIdx.x;
  int lane = threadIdx.x & 63;
  int v = (i < N) ? cnt[i] : 0;
  int x = v;
  #pragma unroll
  for(int d = 1; d < 64; d <<= 1){ int t = __shfl_up(x, d, 64); if(lane >= d) x += t; }
  int base = 0;
  if(lane == 63 && x > 0) base = atomicAdd(total, x);
  base = __shfl(base, 63, 64);
  if(i < N){
    offs[i] = base + x - v;
    dis[i]  = 1.0f / sqrtf((float)(v + 1));
    invc[i] = 1.0f / fmaxf((float)v, 1.0f);
  }
}

// ================= MID: fill(1563) | gate(1) | attdotx(3125) =================
struct MidP {
  const int* row; const int* col; const int* offs; int* cursor; int* csr;
  const float* gsum; const float* w1; const float* b1; const float* w2; const float* b2;
  float* gatew;
  const unsigned short* xb; const float* wsd; float* asrc; float* adst;
};

#define NB_ATT (NN/16)             // 3125

__global__ __launch_bounds__(256) void k_mid(MidP p){
  __shared__ float ws[64*8];
  __shared__ float g[64]; __shared__ float hid[64]; __shared__ float lg[3];
  int b = blockIdx.x, tid = threadIdx.x;
  if(b < NB_CNT){
    int e = b*256 + tid;
    if(e < NE){
      int c = p.col[e];
      int pos = p.offs[c] + atomicAdd(&p.cursor[c], 1);
      p.csr[pos] = p.row[e];
    }
    return;
  }
  if(b == NB_CNT){
    int t = tid;
    if(t < 64) g[t] = p.gsum[t] * (1.0f/(float)NN);
    __syncthreads();
    if(t < 64){
      float acc = p.b1[t];
      for(int i = 0; i < 64; i++) acc += g[i]*p.w1[i*64 + t];
      hid[t] = fmaxf(acc, 0.f);
    }
    __syncthreads();
    if(t < 3){
      float a = p.b2[t];
      for(int j = 0; j < 64; j++) a += hid[j]*p.w2[j*3 + t];
      lg[t] = a;
    }
    __syncthreads();
    if(t == 0){
      float m = fmaxf(lg[0], fmaxf(lg[1], lg[2]));
      float e0 = expf(lg[0]-m), e1 = expf(lg[1]-m), e2 = expf(lg[2]-m);
      float s = e0 + e1 + e2;
      p.gatew[0] = e0/s; p.gatew[1] = e1/s; p.gatew[2] = e2/s;
    }
    return;
  }
  // attdotx
  int lb = b - (NB_CNT + 1);
  ws[tid] = p.wsd[tid];
  ws[tid + 256] = p.wsd[tid + 256];
  __syncthreads();
  int node = lb*16 + (tid >> 4);
  int l = tid & 15;
  if(node >= NN) return;
  uint2 u = *(const uint2*)&p.xb[(size_t)node*64 + l*4];
  float v0 = bflo(u.x), v1 = bfhi(u.x), v2 = bflo(u.y), v3 = bfhi(u.y);
  float s[8];
  #pragma unroll
  for(int h = 0; h < 8; h++){
    s[h] = v0*ws[(l*4+0)*8+h] + v1*ws[(l*4+1)*8+h] + v2*ws[(l*4+2)*8+h] + v3*ws[(l*4+3)*8+h];
  }
  #pragma unroll
  for(int d = 8; d >= 1; d >>= 1){
    #pragma unroll
    for(int h = 0; h < 8; h++) s[h] += __shfl_xor(s[h], d, 16);
  }
  if(l == 0){
    float4 o1; o1.x = s[0]; o1.y = s[1]; o1.z = s[2]; o1.w = s[3];
    float4 o2; o2.x = s[4]; o2.y = s[5]; o2.z = s[6]; o2.w = s[7];
    *(float4*)&p.asrc[node*4] = o1;
    *(float4*)&p.adst[node*4] = o2;
  }
}

// ================= AGG1: layer-1 gather, GAT1 edge weights inline (1 node/wave) =================
struct A1P {
  const unsigned short* xb; const float* asrc1; const float* adst1;
  const int* offs; const int* cnt; const int* csr;
  const float* dis; const float* invc;
  unsigned short* z; unsigned short* agcnx; unsigned short* asagex; int N;
};

__global__ void k_agg1(A1P p){
  int node = blockIdx.x*4 + (threadIdx.x >> 6);
  int lane = threadIdx.x & 63;
  if(node >= p.N) return;
  int half = lane >> 5, subl = lane & 31;
  float4 ad4 = *(const float4*)&p.adst1[node*4];
  float zg[4][2] = {{0,0},{0,0},{0,0},{0,0}};
  float gg[2] = {0,0}, ssv[2] = {0,0}, wsum[4] = {0,0,0,0};
  int e0 = p.offs[node], e1 = e0 + p.cnt[node];
  #pragma unroll 4
  for(int e = e0 + half; e < e1; e += 2){
    int s = p.csr[e];
    float4 as4 = *(const float4*)&p.asrc1[s*4];
    float ds = p.dis[s];
    unsigned int u = *(const unsigned int*)&p.xb[(size_t)s*64 + subl*2];
    float w0 = fexp(lrelu(as4.x + ad4.x));
    float w1 = fexp(lrelu(as4.y + ad4.y));
    float w2 = fexp(lrelu(as4.z + ad4.z));
    float w3 = fexp(lrelu(as4.w + ad4.w));
    float xl = bflo(u), xh = bfhi(u);
    zg[0][0] = fmaf(w0, xl, zg[0][0]); zg[0][1] = fmaf(w0, xh, zg[0][1]);
    zg[1][0] = fmaf(w1, xl, zg[1][0]); zg[1][1] = fmaf(w1, xh, zg[1][1]);
    zg[2][0] = fmaf(w2, xl, zg[2][0]); zg[2][1] = fmaf(w2, xh, zg[2][1]);
    zg[3][0] = fmaf(w3, xl, zg[3][0]); zg[3][1] = fmaf(w3, xh, zg[3][1]);
    gg[0] = fmaf(ds, xl, gg[0]); gg[1] = fmaf(ds, xh, gg[1]);
    ssv[0] += xl; ssv[1] += xh;
    wsum[0] += w0; wsum[1] += w1; wsum[2] += w2; wsum[3] += w3;
  }
  #pragma unroll
  for(int h = 0; h < 4; h++){
    zg[h][0] += __shfl_xor(zg[h][0], 32, 64);
    zg[h][1] += __shfl_xor(zg[h][1], 32, 64);
    wsum[h]  += __shfl_xor(wsum[h], 32, 64);
  }
  gg[0] += __shfl_xor(gg[0], 32, 64); gg[1] += __shfl_xor(gg[1], 32, 64);
  ssv[0] += __shfl_xor(ssv[0], 32, 64); ssv[1] += __shfl_xor(ssv[1], 32, 64);
  if(half == 0){
    unsigned int un = *(const unsigned int*)&p.xb[(size_t)node*64 + subl*2];
    float xl = bflo(un), xh = bfhi(un);
    float4 asn = *(const float4*)&p.asrc1[node*4];
    float s0 = fexp(lrelu(asn.x + ad4.x));
    float s1v = fexp(lrelu(asn.y + ad4.y));
    float s2 = fexp(lrelu(asn.z + ad4.z));
    float s3 = fexp(lrelu(asn.w + ad4.w));
    float rd0 = 1.0f/(wsum[0] + s0), rd1 = 1.0f/(wsum[1] + s1v);
    float rd2 = 1.0f/(wsum[2] + s2), rd3 = 1.0f/(wsum[3] + s3);
    unsigned int* zp = (unsigned int*)&p.z[(size_t)node*256 + subl*2];
    zp[0]  = pack2((zg[0][0] + s0*xl)*rd0,  (zg[0][1] + s0*xh)*rd0);
    zp[32] = pack2((zg[1][0] + s1v*xl)*rd1, (zg[1][1] + s1v*xh)*rd1);
    zp[64] = pack2((zg[2][0] + s2*xl)*rd2,  (zg[2][1] + s2*xh)*rd2);
    zp[96] = pack2((zg[3][0] + s3*xl)*rd3,  (zg[3][1] + s3*xh)*rd3);
    float dc = p.dis[node], ic = p.invc[node];
    *(unsigned int*)&p.agcnx[(size_t)node*64 + subl*2] =
        pack2(dc*fmaf(dc, xl, gg[0]), dc*fmaf(dc, xh, gg[1]));
    *(unsigned int*)&p.asagex[(size_t)node*64 + subl*2] = pack2(ssv[0]*ic, ssv[1]*ic);
  }
}

// ================= AGG2: layer-2 gather, GAT2 edge weights inline (1 node/wave) =================
struct A2P {
  const unsigned short* a1; const unsigned short* s1; const unsigned short* h2;
  const float* asrc2; const float* adst2;
  const int* offs; const int* cnt; const int* csr;
  const float* dis; const float* invc;
  unsigned short* A2agg; unsigned short* S2agg; unsigned short* T2; int N;
};

__global__ void k_agg2(A2P p){
  int node = blockIdx.x*4 + (threadIdx.x >> 6);
  int lane = threadIdx.x & 63;
  if(node >= p.N) return;
  int half = lane >> 5, subl = lane & 31;
  float ad = p.adst2[node];
  float aa[2] = {0,0}, ss[2] = {0,0}, tt[2] = {0,0}, wsum = 0.f;
  int e0 = p.offs[node], e1 = e0 + p.cnt[node];
  #pragma unroll 4
  for(int e = e0 + half; e < e1; e += 2){
    int s = p.csr[e];
    float wv = fexp(lrelu(p.asrc2[s] + ad));
    float ds = p.dis[s];
    unsigned int ua = *(const unsigned int*)&p.a1[(size_t)s*64 + subl*2];
    unsigned int us = *(const unsigned int*)&p.s1[(size_t)s*64 + subl*2];
    unsigned int uh = *(const unsigned int*)&p.h2[(size_t)s*64 + subl*2];
    aa[0] = fmaf(ds, bflo(ua), aa[0]); aa[1] = fmaf(ds, bfhi(ua), aa[1]);
    ss[0] += bflo(us); ss[1] += bfhi(us);
    tt[0] = fmaf(wv, bflo(uh), tt[0]); tt[1] = fmaf(wv, bfhi(uh), tt[1]);
    wsum += wv;
  }
  aa[0] += __shfl_xor(aa[0], 32, 64); aa[1] += __shfl_xor(aa[1], 32, 64);
  ss[0] += __shfl_xor(ss[0], 32, 64); ss[1] += __shfl_xor(ss[1], 32, 64);
  tt[0] += __shfl_xor(tt[0], 32, 64); tt[1] += __shfl_xor(tt[1], 32, 64);
  wsum  += __shfl_xor(wsum, 32, 64);
  if(half == 0){
    float wss = fexp(lrelu(p.asrc2[node] + ad));
    float rd = 1.0f/(wsum + wss);
    unsigned int uan = *(const unsigned int*)&p.a1[(size_t)node*64 + subl*2];
    unsigned int uhn = *(const unsigned int*)&p.h2[(size_t)node*64 + subl*2];
    float dc = p.dis[node], ic = p.invc[node];
    *(unsigned int*)&p.A2agg[(size_t)node*64 + subl*2] =
        pack2(dc*fmaf(dc, bflo(uan), aa[0]), dc*fmaf(dc, bfhi(uan), aa[1]));
    *(unsigned int*)&p.S2agg[(size_t)node*64 + subl*2] = pack2(ss[0]*ic, ss[1]*ic);
    *(unsigned int*)&p.T2[(size_t)node*64 + subl*2] =
        pack2(fmaf(wss, bflo(uhn), tt[0])*rd, fmaf(wss, bfhi(uhn), tt[1])*rd);
  }
}

// ---------------- fused dispatch: y=0 GAT1+2, y=1 GCN1 mm, y=2 SAGE1 mm ----------------
struct MME {
  const unsigned short* A; const unsigned short* Wb;
  const unsigned short* A2; const unsigned short* Wb2;  // optional second segment (K2=64)
  unsigned short* C;
  const float* b; const float* p1; const float* p2;
  int ep;                                               // 1 = BN+relu; 3 = sage
};
struct FSP {
  const unsigned short* z; const unsigned short* wb1; const float* b1;
  const unsigned short* wb2; const float* as2; const float* ad2;
  unsigned short* h2; float* asrc2; float* adst2;
  MME mm[2];
  int N;
};

__global__ __launch_bounds__(256, 4) void k_fused1(FSP p){
  __shared__ unsigned short smem[64*GHP];  // GAT: GH[64][GHP]; mm: 2x [64][72] tables
  const int N = p.N;
  int tid = threadIdx.x;
  int w = tid >> 6, lane = tid & 63, quad = lane >> 4, m16 = lane & 15;
  int rowa = blockIdx.x*64 + w*16 + m16;
  int rowc = rowa < N ? rowa : N - 1;
  int robase = blockIdx.x*64 + w*16 + quad*4;

  if(blockIdx.y == 0){
    // ================= GAT layer1+layer2, one barrier =================
    unsigned short* GH = smem;             // pitch GHP (264 >= 256 row payload)
    int lr = w*16;
    #pragma unroll
    for(int h = 0; h < 4; h++){
      bf16x8 a0 = *(const bf16x8*)&p.z[(size_t)rowc*256 + h*64 + quad*8];
      bf16x8 a1 = *(const bf16x8*)&p.z[(size_t)rowc*256 + h*64 + 32 + quad*8];
      f32x4 acc[4];
      #pragma unroll
      for(int t = 0; t < 4; t++){ acc[t][0]=0.f; acc[t][1]=0.f; acc[t][2]=0.f; acc[t][3]=0.f; }
      #pragma unroll
      for(int t = 0; t < 4; t++){
        const unsigned short* wb = p.wb1 + (size_t)h*4096 + (t*16 + m16)*64;
        bf16x8 b0 = *(const bf16x8*)&wb[quad*8];
        bf16x8 b1v = *(const bf16x8*)&wb[32 + quad*8];
        acc[t] = __builtin_amdgcn_mfma_f32_16x16x32_bf16(a0, b0, acc[t], 0, 0, 0);
        acc[t] = __builtin_amdgcn_mfma_f32_16x16x32_bf16(a1, b1v, acc[t], 0, 0, 0);
      }
      #pragma unroll
      for(int t = 0; t < 4; t++){
        float bv = p.b1[h*64 + t*16 + m16];
        #pragma unroll
        for(int r = 0; r < 4; r++){
          GH[(lr + quad*4 + r)*GHP + h*64 + t*16 + m16] = f2bf(elu1(acc[t][r] + bv));
        }
      }
    }
    __syncthreads();
    f32x4 acc2[4];
    #pragma unroll
    for(int t = 0; t < 4; t++){ acc2[t][0]=0.f; acc2[t][1]=0.f; acc2[t][2]=0.f; acc2[t][3]=0.f; }
    #pragma unroll
    for(int kc = 0; kc < 256; kc += 64){
      bf16x8 a0 = *(const bf16x8*)&GH[(lr + m16)*GHP + kc + quad*8];
      bf16x8 a1 = *(const bf16x8*)&GH[(lr + m16)*GHP + kc + 32 + quad*8];
      #pragma unroll
      for(int t = 0; t < 4; t++){
        const unsigned short* wb = p.wb2 + (size_t)(t*16 + m16)*256 + kc;
        bf16x8 b0 = *(const bf16x8*)&wb[quad*8];
        bf16x8 b1v = *(const bf16x8*)&wb[32 + quad*8];
        acc2[t] = __builtin_amdgcn_mfma_f32_16x16x32_bf16(a0, b0, acc2[t], 0, 0, 0);
        acc2[t] = __builtin_amdgcn_mfma_f32_16x16x32_bf16(a1, b1v, acc2[t], 0, 0, 0);
      }
    }
    #pragma unroll
    for(int t = 0; t < 4; t++){
      int col = t*16 + m16;
      #pragma unroll
      for(int r = 0; r < 4; r++){
        int ro = robase + r;
        if(ro < N) p.h2[(size_t)ro*64 + col] = f2bf(acc2[t][r]);
      }
    }
    float ps[4] = {0,0,0,0}, pd[4] = {0,0,0,0};
    #pragma unroll
    for(int t = 0; t < 4; t++){
      int col = t*16 + m16;
      float a_ = p.as2[col], d_ = p.ad2[col];
      #pragma unroll
      for(int r = 0; r < 4; r++){ ps[r] = fmaf(acc2[t][r], a_, ps[r]); pd[r] = fmaf(acc2[t][r], d_, pd[r]); }
    }
    #pragma unroll
    for(int d = 8; d >= 1; d >>= 1){
      #pragma unroll
      for(int r = 0; r < 4; r++){ ps[r] += __shfl_xor(ps[r], d, 64); pd[r] += __shfl_xor(pd[r], d, 64); }
    }
    if(m16 == 0){
      #pragma unroll
      for(int r = 0; r < 4; r++){
        int ro = robase + r;
        if(ro < N){ p.asrc2[ro] = ps[r]; p.adst2[ro] = pd[r]; }
      }
    }
    return;
  }

  // ================= GCN / SAGE layer-1 matmuls (LDS-staged B) =================
  MME m = p.mm[blockIdx.y - 1];
  unsigned short* Wt  = smem;
  unsigned short* Wt2 = smem + 4608;
  stage_tab(Wt, m.Wb, tid);
  if(m.Wb2) stage_tab(Wt2, m.Wb2, tid);
  __syncthreads();
  f32x4 acc[4];
  #pragma unroll
  for(int t = 0; t < 4; t++){ acc[t][0]=0.f; acc[t][1]=0.f; acc[t][2]=0.f; acc[t][3]=0.f; }
  {
    bf16x8 a0 = *(const bf16x8*)&m.A[(size_t)rowc*64 + quad*8];
    bf16x8 a1 = *(const bf16x8*)&m.A[(size_t)rowc*64 + 32 + quad*8];
    #pragma unroll
    for(int t = 0; t < 4; t++){
      bf16x8 b0 = *(const bf16x8*)&Wt[(t*16 + m16)*72 + quad*8];
      bf16x8 b1 = *(const bf16x8*)&Wt[(t*16 + m16)*72 + 32 + quad*8];
      acc[t] = __builtin_amdgcn_mfma_f32_16x16x32_bf16(a0, b0, acc[t], 0, 0, 0);
      acc[t] = __builtin_amdgcn_mfma_f32_16x16x32_bf16(a1, b1, acc[t], 0, 0, 0);
    }
  }
  if(m.A2){
    bf16x8 a0 = *(const bf16x8*)&m.A2[(size_t)rowc*64 + quad*8];
    bf16x8 a1 = *(const bf16x8*)&m.A2[(size_t)rowc*64 + 32 + quad*8];
    #pragma unroll
    for(int t = 0; t < 4; t++){
      bf16x8 b0 = *(const bf16x8*)&Wt2[(t*16 + m16)*72 + quad*8];
      bf16x8 b1 = *(const bf16x8*)&Wt2[(t*16 + m16)*72 + 32 + quad*8];
      acc[t] = __builtin_amdgcn_mfma_f32_16x16x32_bf16(a0, b0, acc[t], 0, 0, 0);
      acc[t] = __builtin_amdgcn_mfma_f32_16x16x32_bf16(a1, b1, acc[t], 0, 0, 0);
    }
  }
  if(m.ep == 3){
    float v[4][4], n2[4] = {0,0,0,0};
    #pragma unroll
    for(int t = 0; t < 4; t++){
      float bv = m.b[t*16 + m16];
      #pragma unroll
      for(int r = 0; r < 4; r++){ v[t][r] = acc[t][r] + bv; n2[r] = fmaf(v[t][r], v[t][r], n2[r]); }
    }
    #pragma unroll
    for(int d = 8; d >= 1; d >>= 1){
      #pragma unroll
      for(int r = 0; r < 4; r++) n2[r] += __shfl_xor(n2[r], d, 64);
    }
    float inv[4];
    #pragma unroll
    for(int r = 0; r < 4; r++) inv[r] = 1.0f / fmaxf(sqrtf(n2[r]), 1e-12f);
    #pragma unroll
    for(int t = 0; t < 4; t++){
      #pragma unroll
      for(int r = 0; r < 4; r++){
        int ro = robase + r;
        if(ro < N) m.C[(size_t)ro*64 + t*16 + m16] = f2bf(fmaxf(v[t][r]*inv[r], 0.f));
      }
    }
    return;
  }
  // ep == 1: BN + relu
  #pragma unroll
  for(int t = 0; t < 4; t++){
    int col = t*16 + m16;
    float bv = m.b[col];
    float gm = m.p1[col]*rsqrtf(1.0f + 1e-5f);
    float be = m.p2[col];
    #pragma unroll
    for(int r = 0; r < 4; r++){
      int ro = robase + r;
      if(ro < N){
        m.C[(size_t)ro*64 + col] = f2bf(fmaxf((acc[t][r] + bv)*gm + be, 0.f));
      }
    }
  }
}

// ---------------- final: GCN2 mm + SAGE2 dual mm + L2norm + GAT2 add + gate combine ----------------
__global__ __launch_bounds__(256) void k_mm_final(
    const unsigned short* __restrict__ A2agg, const unsigned short* __restrict__ wb_gcn2,
    const float* __restrict__ gcn_b2,
    const unsigned short* __restrict__ S2agg, const unsigned short* __restrict__ wb_wl2,
    const float* __restrict__ bl2,
    const unsigned short* __restrict__ s1, const unsigned short* __restrict__ wb_wr2,
    const unsigned short* __restrict__ T2, const float* __restrict__ gat_b2,
    const float* __restrict__ gatew, float* __restrict__ out, int N){
  __shared__ unsigned short W1s[64*72];
  __shared__ unsigned short W2s[64*72];
  __shared__ unsigned short W3s[64*72];
  int tid = threadIdx.x;
  stage_tab(W1s, wb_gcn2, tid);
  stage_tab(W2s, wb_wl2, tid);
  stage_tab(W3s, wb_wr2, tid);
  __syncthreads();
  int w = tid >> 6, lane = tid & 63, quad = lane >> 4, m16 = lane & 15;
  int rowa = blockIdx.x*64 + w*16 + m16;
  int rowc = rowa < N ? rowa : N - 1;
  f32x4 accg[4], accs[4];
  #pragma unroll
  for(int t = 0; t < 4; t++){
    accg[t][0]=0.f; accg[t][1]=0.f; accg[t][2]=0.f; accg[t][3]=0.f;
    accs[t][0]=0.f; accs[t][1]=0.f; accs[t][2]=0.f; accs[t][3]=0.f;
  }
  {
    bf16x8 a0 = *(const bf16x8*)&A2agg[(size_t)rowc*64 + quad*8];
    bf16x8 a1 = *(const bf16x8*)&A2agg[(size_t)rowc*64 + 32 + quad*8];
    #pragma unroll
    for(int t = 0; t < 4; t++){
      bf16x8 b0 = *(const bf16x8*)&W1s[(t*16 + m16)*72 + quad*8];
      bf16x8 b1 = *(const bf16x8*)&W1s[(t*16 + m16)*72 + 32 + quad*8];
      accg[t] = __builtin_amdgcn_mfma_f32_16x16x32_bf16(a0, b0, accg[t], 0, 0, 0);
      accg[t] = __builtin_amdgcn_mfma_f32_16x16x32_bf16(a1, b1, accg[t], 0, 0, 0);
    }
  }
  {
    bf16x8 a0 = *(const bf16x8*)&S2agg[(size_t)rowc*64 + quad*8];
    bf16x8 a1 = *(const bf16x8*)&S2agg[(size_t)rowc*64 + 32 + quad*8];
    #pragma unroll
    for(int t = 0; t < 4; t++){
      bf16x8 b0 = *(const bf16x8*)&W2s[(t*16 + m16)*72 + quad*8];
      bf16x8 b1 = *(const bf16x8*)&W2s[(t*16 + m16)*72 + 32 + quad*8];
      accs[t] = __builtin_amdgcn_mfma_f32_16x16x32_bf16(a0, b0, accs[t], 0, 0, 0);
      accs[t] = __builtin_amdgcn_mfma_f32_16x16x32_bf16(a1, b1, accs[t], 0, 0, 0);
    }
  }
  {
    bf16x8 a0 = *(const bf16x8*)&s1[(size_t)rowc*64 + quad*8];
    bf16x8 a1 = *(const bf16x8*)&s1[(size_t)rowc*64 + 32 + quad*8];
    #pragma unroll
    for(int t = 0; t < 4; t++){
      bf16x8 b0 = *(const bf16x8*)&W3s[(t*16 + m16)*72 + quad*8];
      bf16x8 b1 = *(const bf16x8*)&W3s[(t*16 + m16)*72 + 32 + quad*8];
      accs[t] = __builtin_amdgcn_mfma_f32_16x16x32_bf16(a0, b0, accs[t], 0, 0, 0);
      accs[t] = __builtin_amdgcn_mfma_f32_16x16x32_bf16(a1, b1, accs[t], 0, 0, 0);
    }
  }
  float w0 = gatew[0], w1 = gatew[1], w2 = gatew[2];
  int robase = blockIdx.x*64 + w*16 + quad*4;
  float vs[4][4], n2[4] = {0,0,0,0};
  #pragma unroll
  for(int t = 0; t < 4; t++){
    float bsv = bl2[t*16 + m16];
    #pragma unroll
    for(int r = 0; r < 4; r++){ vs[t][r] = accs[t][r] + bsv; n2[r] = fmaf(vs[t][r], vs[t][r], n2[r]); }
  }
  #pragma unroll
  for(int d = 8; d >= 1; d >>= 1){
    #pragma unroll
    for(int r = 0; r < 4; r++) n2[r] += __shfl_xor(n2[r], d, 64);
  }
  float inv[4];
  #pragma unroll
  for(int r = 0; r < 4; r++) inv[r] = 1.0f / fmaxf(sqrtf(n2[r]), 1e-12f);
  #pragma unroll
  for(int t = 0; t < 4; t++){
    int col = t*16 + m16;
    float bg = gcn_b2[col], bt = gat_b2[col];
    #pragma unroll
    for(int r = 0; r < 4; r++){
      int ro = robase + r;
      if(ro < N){
        float t2 = bflo((unsigned int)T2[(size_t)ro*64 + col]);
        out[(size_t)ro*64 + col] = w0*(accg[t][r] + bg) + w1*(t2 + bt) + w2*vs[t][r]*inv[r];
      }
    }
  }
}

// ---------------- host ----------------
extern "C" void kernel_launch(void* const* d_in, const int* in_sizes, int n_in,
                              void* d_out, int out_size, void* d_ws, size_t ws_size,
                              hipStream_t stream){
  const float* x        = (const float*)d_in[0];
  const int*   ei       = (const int*)d_in[1];
  const int*   row      = ei;
  const int*   col      = ei + NE;
  const float* gate_w1  = (const float*)d_in[2];
  const float* gate_b1  = (const float*)d_in[3];
  const float* gate_w2  = (const float*)d_in[4];
  const float* gate_b2  = (const float*)d_in[5];
  const float* gcn_w1   = (const float*)d_in[6];
  const float* gcn_b1   = (const float*)d_in[7];
  const float* bn_gamma = (const float*)d_in[8];
  const float* bn_beta  = (const float*)d_in[9];
  const float* gcn_w2   = (const float*)d_in[10];
  const float* gcn_b2   = (const float*)d_in[11];
  const float* gat_w1   = (const float*)d_in[12];
  const float* gat_as1  = (const float*)d_in[13];
  const float* gat_ad1  = (const float*)d_in[14];
  const float* gat_b1   = (const float*)d_in[15];
  const float* gat_w2   = (const float*)d_in[16];
  const float* gat_as2  = (const float*)d_in[17];
  const float* gat_ad2  = (const float*)d_in[18];
  const float* gat_b2   = (const float*)d_in[19];
  const float* sage_wl1 = (const float*)d_in[20];
  const float* sage_bl1 = (const float*)d_in[21];
  const float* sage_wr1 = (const float*)d_in[22];
  const float* sage_wl2 = (const float*)d_in[23];
  const float* sage_bl2 = (const float*)d_in[24];
  const float* sage_wr2 = (const float*)d_in[25];
  float* out = (float*)d_out;

  char* wp = (char*)d_ws;
  auto alloc = [&](size_t bytes)->char*{ char* p = wp; wp += (bytes + 255) & ~(size_t)255; return p; };
  // zero-init region (contiguous): cnt, cursor, gsum, total
  int*   cnt    = (int*)  alloc((size_t)NN*4);
  int*   cursor = (int*)  alloc((size_t)NN*4);
  float* gsum   = (float*)alloc(64*4);
  int*   total  = (int*)  alloc(256);
  size_t zbytes = (size_t)(wp - (char*)cnt);
  int*   offs   = (int*)  alloc((size_t)NN*4);
  int*   csr    = (int*)  alloc((size_t)NE*4);
  float* dis    = (float*)alloc((size_t)NN*4);
  float* invc   = (float*)alloc((size_t)NN*4);
  float* gatew  = (float*)alloc(16);
  float* wsd    = (float*)alloc(64*8*4);
  float* asrc1  = (float*)alloc((size_t)NN*4*4);
  float* adst1  = (float*)alloc((size_t)NN*4*4);
  float* asrc2  = (float*)alloc((size_t)NN*4);
  float* adst2  = (float*)alloc((size_t)NN*4);
  unsigned short* xb     = (unsigned short*)alloc((size_t)NN*64*2);
  unsigned short* z      = (unsigned short*)alloc((size_t)NN*256*2);
  unsigned short* agcnx  = (unsigned short*)alloc((size_t)NN*64*2);
  unsigned short* asagex = (unsigned short*)alloc((size_t)NN*64*2);
  unsigned short* a1     = (unsigned short*)alloc((size_t)NN*64*2);
  unsigned short* s1     = (unsigned short*)alloc((size_t)NN*64*2);
  unsigned short* h2     = (unsigned short*)alloc((size_t)NN*64*2);
  unsigned short* A2agg  = (unsigned short*)alloc((size_t)NN*64*2);
  unsigned short* S2agg  = (unsigned short*)alloc((size_t)NN*64*2);
  unsigned short* T2     = (unsigned short*)alloc((size_t)NN*64*2);
  // packed bf16 weights (B-operand layout [n][K])
  unsigned short* wb_gcn1 = (unsigned short*)alloc((size_t)64*64*2);
  unsigned short* wb_wl1  = (unsigned short*)alloc((size_t)64*64*2);
  unsigned short* wb_wr1  = (unsigned short*)alloc((size_t)64*64*2);
  unsigned short* wb_gat1 = (unsigned short*)alloc((size_t)256*64*2);
  unsigned short* wb_gat2 = (unsigned short*)alloc((size_t)64*256*2);
  unsigned short* wb_gcn2 = (unsigned short*)alloc((size_t)64*64*2);
  unsigned short* wb_wl2  = (unsigned short*)alloc((size_t)64*64*2);
  unsigned short* wb_wr2  = (unsigned short*)alloc((size_t)64*64*2);

  hipMemsetAsync(cnt, 0, zbytes, stream);

  const int gN  = (NN + 63) / 64;   // 782
  const int g4  = NN / 4;           // 12500
  const int gA  = (NN + 255) / 256; // 196

  // ---- pre: packw | count | castsum | fold1 ----
  {
    PreP p = {};
    p.pk[0]  = {gcn_w1,   wb_gcn1,            6, 64,  0};
    p.pk[1]  = {sage_wl1, wb_wl1,             6, 64,  0};
    p.pk[2]  = {sage_wr1, wb_wr1,             6, 64,  0};
    p.pk[3]  = {gat_w1,   wb_gat1 + 0*64*64,  6, 256, 0};
    p.pk[4]  = {gat_w1,   wb_gat1 + 1*64*64,  6, 256, 64};
    p.pk[5]  = {gat_w1,   wb_gat1 + 2*64*64,  6, 256, 128};
    p.pk[6]  = {gat_w1,   wb_gat1 + 3*64*64,  6, 256, 192};
    p.pk[7]  = {gat_w2,   wb_gat2,            8, 64,  0};
    p.pk[8]  = {gcn_w2,   wb_gcn2,            6, 64,  0};
    p.pk[9]  = {sage_wl2, wb_wl2,             6, 64,  0};
    p.pk[10] = {sage_wr2, wb_wr2,             6, 64,  0};
    p.col = col; p.cnt = cnt;
    p.x = x; p.xb = xb; p.gsum = gsum;
    p.gw1 = gat_w1; p.gas = gat_as1; p.gad = gat_ad1; p.wsd = wsd;
    k_pre<<<11 + NB_CNT + 256 + 1, 256, 0, stream>>>(p);
  }

  k_alloc<<<gA, 256, 0, stream>>>(cnt, offs, dis, invc, total, NN);

  // ---- mid: fill | gate | attdotx ----
  {
    MidP p = {};
    p.row = row; p.col = col; p.offs = offs; p.cursor = cursor; p.csr = csr;
    p.gsum = gsum; p.w1 = gate_w1; p.b1 = gate_b1; p.w2 = gate_w2; p.b2 = gate_b2;
    p.gatew = gatew;
    p.xb = xb; p.wsd = wsd; p.asrc = asrc1; p.adst = adst1;
    k_mid<<<NB_CNT + 1 + NB_ATT, 256, 0, stream>>>(p);
  }

  // ---- layer-1 gather with inline GAT1 edge weights ----
  {
    A1P p = {};
    p.xb = xb; p.asrc1 = asrc1; p.adst1 = adst1;
    p.offs = offs; p.cnt = cnt; p.csr = csr; p.dis = dis; p.invc = invc;
    p.z = z; p.agcnx = agcnx; p.asagex = asagex; p.N = NN;
    k_agg1<<<g4, 256, 0, stream>>>(p);
  }

  // ---- fused: GAT1+GAT2 (y=0), GCN1 mm (y=1), SAGE1 mm (y=2) ----
  {
    FSP p = {};
    p.N = NN;
    p.z = z; p.wb1 = wb_gat1; p.b1 = gat_b1;
    p.wb2 = wb_gat2; p.as2 = gat_as2; p.ad2 = gat_ad2;
    p.h2 = h2; p.asrc2 = asrc2; p.adst2 = adst2;
    p.mm[0] = {agcnx, wb_gcn1, nullptr, nullptr, a1, gcn_b1, bn_gamma, bn_beta, 1};
    p.mm[1] = {asagex, wb_wl1, xb, wb_wr1, s1, sage_bl1, nullptr, nullptr, 3};
    k_fused1<<<dim3(gN,3), 256, 0, stream>>>(p);
  }

  // ---- layer-2 gather with inline GAT2 edge weights ----
  {
    A2P p = {};
    p.a1 = a1; p.s1 = s1; p.h2 = h2; p.asrc2 = asrc2; p.adst2 = adst2;
    p.offs = offs; p.cnt = cnt; p.csr = csr; p.dis = dis; p.invc = invc;
    p.A2agg = A2agg; p.S2agg = S2agg; p.T2 = T2; p.N = NN;
    k_agg2<<<g4, 256, 0, stream>>>(p);
  }

  // ---- final matmuls + gate combine ----
  k_mm_final<<<gN, 256, 0, stream>>>(A2agg, wb_gcn2, gcn_b2, S2agg, wb_wl2, sage_bl2,
                                     s1, wb_wr2, T2, gat_b2, gatew, out, NN);
}

// Round 12
// 304.803 us; speedup vs baseline: 1.0176x; 1.0107x over previous
//
#include <hip/hip_runtime.h>
#include <hip/hip_bf16.h>
#include <math.h>

#define NN 50000
#define NE 400000

typedef __attribute__((ext_vector_type(8))) short bf16x8;
typedef __attribute__((ext_vector_type(4))) float f32x4;

// GH LDS pitch: row payload is 256 elems (4 heads x 64); min 16B-aligned pitch > 256 is 264.
#define GHP 264

// ---------------- helpers ----------------
__device__ __forceinline__ float lrelu(float v){ return v > 0.f ? v : 0.2f*v; }
__device__ __forceinline__ float elu1(float v){ return v > 0.f ? v : __expf(v) - 1.0f; }
__device__ __forceinline__ float fexp(float v){ return __expf(v); }
__device__ __forceinline__ float bflo(unsigned int u){ return __uint_as_float(u << 16); }
__device__ __forceinline__ float bfhi(unsigned int u){ return __uint_as_float(u & 0xffff0000u); }
__device__ __forceinline__ unsigned short f2bf(float f){
  __hip_bfloat16 h = __float2bfloat16(f);
  return *(unsigned short*)&h;
}
__device__ __forceinline__ unsigned int pack2(float lo, float hi){
  return (unsigned int)f2bf(lo) | ((unsigned int)f2bf(hi) << 16);
}

// stage a packed bf16 [64][64] table into LDS with pitch 72 (2-way-free reads)
__device__ __forceinline__ void stage_tab(unsigned short* Wt, const unsigned short* Wb, int tid){
  #pragma unroll
  for(int s = 0; s < 2; s++){
    int c = tid + s*256;           // 512 chunks of 8 elems
    int n = c >> 3, ko = (c & 7)*8;
    *(bf16x8*)&Wt[n*72 + ko] = *(const bf16x8*)&Wb[n*64 + ko];
  }
}

// ---------------- pack weights descriptor ----------------
struct PKS { const float* src; unsigned short* dst; int kshift; int ldw; int col0; };

// ================= PRE: packw(11) | count(1563) | castsum(256) | fold1(1) =================
struct PreP {
  PKS pk[11];
  const int* col; int* cnt;
  const float* x; unsigned short* xb; float* gsum;
  const float* gw1; const float* gas; const float* gad; float* wsd;
};

#define NB_CNT ((NE+255)/256)      // 1563

__global__ __launch_bounds__(256) void k_pre(PreP p){
  __shared__ float part[4][64];
  int b = blockIdx.x, tid = threadIdx.x;
  if(b < 11){
    PKS s = p.pk[b];
    int K = 1 << s.kshift;
    int total = K << 6;
    for(int idx = tid; idx < total; idx += 256){
      int n = idx >> s.kshift, k = idx & (K - 1);
      s.dst[idx] = f2bf(s.src[(size_t)k*s.ldw + s.col0 + n]);
    }
    return;
  }
  if(b < 11 + NB_CNT){
    int e = (b - 11)*256 + tid;
    if(e < NE) atomicAdd(&p.cnt[p.col[e]], 1);
    return;
  }
  if(b < 11 + NB_CNT + 256){
    int lb = b - (11 + NB_CNT);
    int lane = tid & 63, w = tid >> 6;
    float s = 0.f;
    for(int r = lb*4 + w; r < NN; r += 256*4){
      float v = p.x[(size_t)r*64 + lane];
      p.xb[(size_t)r*64 + lane] = f2bf(v);
      s += v;
    }
    part[w][lane] = s;
    __syncthreads();
    if(w == 0) atomicAdd(&p.gsum[lane], part[0][lane]+part[1][lane]+part[2][lane]+part[3][lane]);
    return;
  }
  // fold1
  {
    int k = tid & 63, h = tid >> 6;
    float ssrc = 0.f, sdst = 0.f;
    for(int c = 0; c < 64; c++){
      float w = p.gw1[k*256 + h*64 + c];
      ssrc += w * p.gas[h*64 + c];
      sdst += w * p.gad[h*64 + c];
    }
    p.wsd[k*8 + h] = ssrc;
    p.wsd[k*8 + 4 + h] = sdst;
  }
}

// ---------------- CSR alloc (scan) ----------------
__global__ void k_alloc(const int* __restrict__ cnt, int* __restrict__ offs,
                        float* __restrict__ dis, float* __restrict__ invc,
                        int* __restrict__ total, int N){
  int i = blockIdx.x*blockDim.x + threadIdx.x;
  int lane = threadIdx.x & 63;
  int v = (i < N) ? cnt[i] : 0;
  int x = v;
  #pragma unroll
  for(int d = 1; d < 64; d <<= 1){ int t = __shfl_up(x, d, 64); if(lane >= d) x += t; }
  int base = 0;
  if(lane == 63 && x > 0) base = atomicAdd(total, x);
  base = __shfl(base, 63, 64);
  if(i < N){
    offs[i] = base + x - v;
    dis[i]  = 1.0f / sqrtf((float)(v + 1));
    invc[i] = 1.0f / fmaxf((float)v, 1.0f);
  }
}

// ================= MID: fill(1563) | gate(1) | attdotx(3125) =================
struct MidP {
  const int* row; const int* col; const int* offs; int* cursor; int* csr;
  const float* gsum; const float* w1; const float* b1; const float* w2; const float* b2;
  float* gatew;
  const unsigned short* xb; const float* wsd;
  const float* dis; const float* invc;
  float* pa1;          // [N][8]: {asrc1[0..3], dis, invc, pad, pad}
  float* adst;         // [N][4]
};

#define NB_ATT (NN/16)             // 3125

__global__ __launch_bounds__(256) void k_mid(MidP p){
  __shared__ float ws[64*8];
  __shared__ float g[64]; __shared__ float hid[64]; __shared__ float lg[3];
  int b = blockIdx.x, tid = threadIdx.x;
  if(b < NB_CNT){
    int e = b*256 + tid;
    if(e < NE){
      int c = p.col[e];
      int pos = p.offs[c] + atomicAdd(&p.cursor[c], 1);
      p.csr[pos] = p.row[e];
    }
    return;
  }
  if(b == NB_CNT){
    int t = tid;
    if(t < 64) g[t] = p.gsum[t] * (1.0f/(float)NN);
    __syncthreads();
    if(t < 64){
      float acc = p.b1[t];
      for(int i = 0; i < 64; i++) acc += g[i]*p.w1[i*64 + t];
      hid[t] = fmaxf(acc, 0.f);
    }
    __syncthreads();
    if(t < 3){
      float a = p.b2[t];
      for(int j = 0; j < 64; j++) a += hid[j]*p.w2[j*3 + t];
      lg[t] = a;
    }
    __syncthreads();
    if(t == 0){
      float m = fmaxf(lg[0], fmaxf(lg[1], lg[2]));
      float e0 = expf(lg[0]-m), e1 = expf(lg[1]-m), e2 = expf(lg[2]-m);
      float s = e0 + e1 + e2;
      p.gatew[0] = e0/s; p.gatew[1] = e1/s; p.gatew[2] = e2/s;
    }
    return;
  }
  // attdotx
  int lb = b - (NB_CNT + 1);
  ws[tid] = p.wsd[tid];
  ws[tid + 256] = p.wsd[tid + 256];
  __syncthreads();
  int node = lb*16 + (tid >> 4);
  int l = tid & 15;
  if(node >= NN) return;
  uint2 u = *(const uint2*)&p.xb[(size_t)node*64 + l*4];
  float v0 = bflo(u.x), v1 = bfhi(u.x), v2 = bflo(u.y), v3 = bfhi(u.y);
  float s[8];
  #pragma unroll
  for(int h = 0; h < 8; h++){
    s[h] = v0*ws[(l*4+0)*8+h] + v1*ws[(l*4+1)*8+h] + v2*ws[(l*4+2)*8+h] + v3*ws[(l*4+3)*8+h];
  }
  #pragma unroll
  for(int d = 8; d >= 1; d >>= 1){
    #pragma unroll
    for(int h = 0; h < 8; h++) s[h] += __shfl_xor(s[h], d, 16);
  }
  if(l == 0){
    float4 o1; o1.x = s[0]; o1.y = s[1]; o1.z = s[2]; o1.w = s[3];
    *(float4*)&p.pa1[(size_t)node*8] = o1;
    float2 o3; o3.x = p.dis[node]; o3.y = p.invc[node];
    *(float2*)&p.pa1[(size_t)node*8 + 4] = o3;
    float4 o2; o2.x = s[4]; o2.y = s[5]; o2.z = s[6]; o2.w = s[7];
    *(float4*)&p.adst[(size_t)node*4] = o2;
  }
}

// ================= AGG1: layer-1 gather, GAT1 edge weights inline (1 node/wave) =================
// Per-edge scattered lines: pa1[s] (asrc+dis one line) + xb[s] — was 3 (asrc, dis, xb).
struct A1P {
  const unsigned short* xb; const float* pa1; const float* adst1;
  const int* offs; const int* cnt; const int* csr;
  unsigned short* z; unsigned short* agcnx; unsigned short* asagex; int N;
};

__global__ void k_agg1(A1P p){
  int node = blockIdx.x*4 + (threadIdx.x >> 6);
  int lane = threadIdx.x & 63;
  if(node >= p.N) return;
  int half = lane >> 5, subl = lane & 31;
  float4 ad4 = *(const float4*)&p.adst1[(size_t)node*4];
  float zg[4][2] = {{0,0},{0,0},{0,0},{0,0}};
  float gg[2] = {0,0}, ssv[2] = {0,0}, wsum[4] = {0,0,0,0};
  int e0 = p.offs[node], e1 = e0 + p.cnt[node];
  #pragma unroll 4
  for(int e = e0 + half; e < e1; e += 2){
    int s = p.csr[e];
    float4 as4 = *(const float4*)&p.pa1[(size_t)s*8];
    float ds = p.pa1[(size_t)s*8 + 4];
    unsigned int u = *(const unsigned int*)&p.xb[(size_t)s*64 + subl*2];
    float w0 = fexp(lrelu(as4.x + ad4.x));
    float w1 = fexp(lrelu(as4.y + ad4.y));
    float w2 = fexp(lrelu(as4.z + ad4.z));
    float w3 = fexp(lrelu(as4.w + ad4.w));
    float xl = bflo(u), xh = bfhi(u);
    zg[0][0] = fmaf(w0, xl, zg[0][0]); zg[0][1] = fmaf(w0, xh, zg[0][1]);
    zg[1][0] = fmaf(w1, xl, zg[1][0]); zg[1][1] = fmaf(w1, xh, zg[1][1]);
    zg[2][0] = fmaf(w2, xl, zg[2][0]); zg[2][1] = fmaf(w2, xh, zg[2][1]);
    zg[3][0] = fmaf(w3, xl, zg[3][0]); zg[3][1] = fmaf(w3, xh, zg[3][1]);
    gg[0] = fmaf(ds, xl, gg[0]); gg[1] = fmaf(ds, xh, gg[1]);
    ssv[0] += xl; ssv[1] += xh;
    wsum[0] += w0; wsum[1] += w1; wsum[2] += w2; wsum[3] += w3;
  }
  #pragma unroll
  for(int h = 0; h < 4; h++){
    zg[h][0] += __shfl_xor(zg[h][0], 32, 64);
    zg[h][1] += __shfl_xor(zg[h][1], 32, 64);
    wsum[h]  += __shfl_xor(wsum[h], 32, 64);
  }
  gg[0] += __shfl_xor(gg[0], 32, 64); gg[1] += __shfl_xor(gg[1], 32, 64);
  ssv[0] += __shfl_xor(ssv[0], 32, 64); ssv[1] += __shfl_xor(ssv[1], 32, 64);
  if(half == 0){
    unsigned int un = *(const unsigned int*)&p.xb[(size_t)node*64 + subl*2];
    float xl = bflo(un), xh = bfhi(un);
    float4 asn = *(const float4*)&p.pa1[(size_t)node*8];
    float dc = p.pa1[(size_t)node*8 + 4];
    float ic = p.pa1[(size_t)node*8 + 5];
    float s0 = fexp(lrelu(asn.x + ad4.x));
    float s1v = fexp(lrelu(asn.y + ad4.y));
    float s2 = fexp(lrelu(asn.z + ad4.z));
    float s3 = fexp(lrelu(asn.w + ad4.w));
    float rd0 = 1.0f/(wsum[0] + s0), rd1 = 1.0f/(wsum[1] + s1v);
    float rd2 = 1.0f/(wsum[2] + s2), rd3 = 1.0f/(wsum[3] + s3);
    unsigned int* zp = (unsigned int*)&p.z[(size_t)node*256 + subl*2];
    zp[0]  = pack2((zg[0][0] + s0*xl)*rd0,  (zg[0][1] + s0*xh)*rd0);
    zp[32] = pack2((zg[1][0] + s1v*xl)*rd1, (zg[1][1] + s1v*xh)*rd1);
    zp[64] = pack2((zg[2][0] + s2*xl)*rd2,  (zg[2][1] + s2*xh)*rd2);
    zp[96] = pack2((zg[3][0] + s3*xl)*rd3,  (zg[3][1] + s3*xh)*rd3);
    *(unsigned int*)&p.agcnx[(size_t)node*64 + subl*2] =
        pack2(dc*fmaf(dc, xl, gg[0]), dc*fmaf(dc, xh, gg[1]));
    *(unsigned int*)&p.asagex[(size_t)node*64 + subl*2] = pack2(ssv[0]*ic, ssv[1]*ic);
  }
}

// ================= AGG2: layer-2 gather, GAT2 edge weights inline (1 node/wave) =================
// pa2[N][4] = {asrc2, dis, invc, adst2}: one float4 per edge replaces asrc2+dis loads.
struct A2P {
  const unsigned short* a1; const unsigned short* s1; const unsigned short* h2;
  const float* pa2;
  const int* offs; const int* cnt; const int* csr;
  unsigned short* A2agg; unsigned short* S2agg; unsigned short* T2; int N;
};

__global__ void k_agg2(A2P p){
  int node = blockIdx.x*4 + (threadIdx.x >> 6);
  int lane = threadIdx.x & 63;
  if(node >= p.N) return;
  int half = lane >> 5, subl = lane & 31;
  float4 pn = *(const float4*)&p.pa2[(size_t)node*4];   // {asrc_n, dc, ic, ad}
  float ad = pn.w;
  float aa[2] = {0,0}, ss[2] = {0,0}, tt[2] = {0,0}, wsum = 0.f;
  int e0 = p.offs[node], e1 = e0 + p.cnt[node];
  #pragma unroll 4
  for(int e = e0 + half; e < e1; e += 2){
    int s = p.csr[e];
    float4 pe = *(const float4*)&p.pa2[(size_t)s*4];
    float wv = fexp(lrelu(pe.x + ad));
    float ds = pe.y;
    unsigned int ua = *(const unsigned int*)&p.a1[(size_t)s*64 + subl*2];
    unsigned int us = *(const unsigned int*)&p.s1[(size_t)s*64 + subl*2];
    unsigned int uh = *(const unsigned int*)&p.h2[(size_t)s*64 + subl*2];
    aa[0] = fmaf(ds, bflo(ua), aa[0]); aa[1] = fmaf(ds, bfhi(ua), aa[1]);
    ss[0] += bflo(us); ss[1] += bfhi(us);
    tt[0] = fmaf(wv, bflo(uh), tt[0]); tt[1] = fmaf(wv, bfhi(uh), tt[1]);
    wsum += wv;
  }
  aa[0] += __shfl_xor(aa[0], 32, 64); aa[1] += __shfl_xor(aa[1], 32, 64);
  ss[0] += __shfl_xor(ss[0], 32, 64); ss[1] += __shfl_xor(ss[1], 32, 64);
  tt[0] += __shfl_xor(tt[0], 32, 64); tt[1] += __shfl_xor(tt[1], 32, 64);
  wsum  += __shfl_xor(wsum, 32, 64);
  if(half == 0){
    float wss = fexp(lrelu(pn.x + ad));
    float rd = 1.0f/(wsum + wss);
    float dc = pn.y, ic = pn.z;
    unsigned int uan = *(const unsigned int*)&p.a1[(size_t)node*64 + subl*2];
    unsigned int uhn = *(const unsigned int*)&p.h2[(size_t)node*64 + subl*2];
    *(unsigned int*)&p.A2agg[(size_t)node*64 + subl*2] =
        pack2(dc*fmaf(dc, bflo(uan), aa[0]), dc*fmaf(dc, bfhi(uan), aa[1]));
    *(unsigned int*)&p.S2agg[(size_t)node*64 + subl*2] = pack2(ss[0]*ic, ss[1]*ic);
    *(unsigned int*)&p.T2[(size_t)node*64 + subl*2] =
        pack2(fmaf(wss, bflo(uhn), tt[0])*rd, fmaf(wss, bfhi(uhn), tt[1])*rd);
  }
}

// ---------------- fused dispatch: y=0 GAT1+2, y=1 GCN1 mm, y=2 SAGE1 mm ----------------
struct MME {
  const unsigned short* A; const unsigned short* Wb;
  const unsigned short* A2; const unsigned short* Wb2;  // optional second segment (K2=64)
  unsigned short* C;
  const float* b; const float* p1; const float* p2;
  int ep;                                               // 1 = BN+relu; 3 = sage
};
struct FSP {
  const unsigned short* z; const unsigned short* wb1; const float* b1;
  const unsigned short* wb2; const float* as2; const float* ad2;
  unsigned short* h2; float* pa2;
  const float* dis; const float* invc;
  MME mm[2];
  int N;
};

__global__ __launch_bounds__(256, 4) void k_fused1(FSP p){
  __shared__ unsigned short smem[64*GHP];  // GAT: GH[64][GHP]; mm: 2x [64][72] tables
  const int N = p.N;
  int tid = threadIdx.x;
  int w = tid >> 6, lane = tid & 63, quad = lane >> 4, m16 = lane & 15;
  int rowa = blockIdx.x*64 + w*16 + m16;
  int rowc = rowa < N ? rowa : N - 1;
  int robase = blockIdx.x*64 + w*16 + quad*4;

  if(blockIdx.y == 0){
    // ================= GAT layer1+layer2, one barrier =================
    unsigned short* GH = smem;             // pitch GHP (264 >= 256 row payload)
    int lr = w*16;
    #pragma unroll
    for(int h = 0; h < 4; h++){
      bf16x8 a0 = *(const bf16x8*)&p.z[(size_t)rowc*256 + h*64 + quad*8];
      bf16x8 a1 = *(const bf16x8*)&p.z[(size_t)rowc*256 + h*64 + 32 + quad*8];
      f32x4 acc[4];
      #pragma unroll
      for(int t = 0; t < 4; t++){ acc[t][0]=0.f; acc[t][1]=0.f; acc[t][2]=0.f; acc[t][3]=0.f; }
      #pragma unroll
      for(int t = 0; t < 4; t++){
        const unsigned short* wb = p.wb1 + (size_t)h*4096 + (t*16 + m16)*64;
        bf16x8 b0 = *(const bf16x8*)&wb[quad*8];
        bf16x8 b1v = *(const bf16x8*)&wb[32 + quad*8];
        acc[t] = __builtin_amdgcn_mfma_f32_16x16x32_bf16(a0, b0, acc[t], 0, 0, 0);
        acc[t] = __builtin_amdgcn_mfma_f32_16x16x32_bf16(a1, b1v, acc[t], 0, 0, 0);
      }
      #pragma unroll
      for(int t = 0; t < 4; t++){
        float bv = p.b1[h*64 + t*16 + m16];
        #pragma unroll
        for(int r = 0; r < 4; r++){
          GH[(lr + quad*4 + r)*GHP + h*64 + t*16 + m16] = f2bf(elu1(acc[t][r] + bv));
        }
      }
    }
    __syncthreads();
    f32x4 acc2[4];
    #pragma unroll
    for(int t = 0; t < 4; t++){ acc2[t][0]=0.f; acc2[t][1]=0.f; acc2[t][2]=0.f; acc2[t][3]=0.f; }
    #pragma unroll
    for(int kc = 0; kc < 256; kc += 64){
      bf16x8 a0 = *(const bf16x8*)&GH[(lr + m16)*GHP + kc + quad*8];
      bf16x8 a1 = *(const bf16x8*)&GH[(lr + m16)*GHP + kc + 32 + quad*8];
      #pragma unroll
      for(int t = 0; t < 4; t++){
        const unsigned short* wb = p.wb2 + (size_t)(t*16 + m16)*256 + kc;
        bf16x8 b0 = *(const bf16x8*)&wb[quad*8];
        bf16x8 b1v = *(const bf16x8*)&wb[32 + quad*8];
        acc2[t] = __builtin_amdgcn_mfma_f32_16x16x32_bf16(a0, b0, acc2[t], 0, 0, 0);
        acc2[t] = __builtin_amdgcn_mfma_f32_16x16x32_bf16(a1, b1v, acc2[t], 0, 0, 0);
      }
    }
    #pragma unroll
    for(int t = 0; t < 4; t++){
      int col = t*16 + m16;
      #pragma unroll
      for(int r = 0; r < 4; r++){
        int ro = robase + r;
        if(ro < N) p.h2[(size_t)ro*64 + col] = f2bf(acc2[t][r]);
      }
    }
    float ps[4] = {0,0,0,0}, pd[4] = {0,0,0,0};
    #pragma unroll
    for(int t = 0; t < 4; t++){
      int col = t*16 + m16;
      float a_ = p.as2[col], d_ = p.ad2[col];
      #pragma unroll
      for(int r = 0; r < 4; r++){ ps[r] = fmaf(acc2[t][r], a_, ps[r]); pd[r] = fmaf(acc2[t][r], d_, pd[r]); }
    }
    #pragma unroll
    for(int d = 8; d >= 1; d >>= 1){
      #pragma unroll
      for(int r = 0; r < 4; r++){ ps[r] += __shfl_xor(ps[r], d, 64); pd[r] += __shfl_xor(pd[r], d, 64); }
    }
    if(m16 == 0){
      #pragma unroll
      for(int r = 0; r < 4; r++){
        int ro = robase + r;
        if(ro < N){
          float4 o; o.x = ps[r]; o.y = p.dis[ro]; o.z = p.invc[ro]; o.w = pd[r];
          *(float4*)&p.pa2[(size_t)ro*4] = o;
        }
      }
    }
    return;
  }

  // ================= GCN / SAGE layer-1 matmuls (LDS-staged B) =================
  MME m = p.mm[blockIdx.y - 1];
  unsigned short* Wt  = smem;
  unsigned short* Wt2 = smem + 4608;
  stage_tab(Wt, m.Wb, tid);
  if(m.Wb2) stage_tab(Wt2, m.Wb2, tid);
  __syncthreads();
  f32x4 acc[4];
  #pragma unroll
  for(int t = 0; t < 4; t++){ acc[t][0]=0.f; acc[t][1]=0.f; acc[t][2]=0.f; acc[t][3]=0.f; }
  {
    bf16x8 a0 = *(const bf16x8*)&m.A[(size_t)rowc*64 + quad*8];
    bf16x8 a1 = *(const bf16x8*)&m.A[(size_t)rowc*64 + 32 + quad*8];
    #pragma unroll
    for(int t = 0; t < 4; t++){
      bf16x8 b0 = *(const bf16x8*)&Wt[(t*16 + m16)*72 + quad*8];
      bf16x8 b1 = *(const bf16x8*)&Wt[(t*16 + m16)*72 + 32 + quad*8];
      acc[t] = __builtin_amdgcn_mfma_f32_16x16x32_bf16(a0, b0, acc[t], 0, 0, 0);
      acc[t] = __builtin_amdgcn_mfma_f32_16x16x32_bf16(a1, b1, acc[t], 0, 0, 0);
    }
  }
  if(m.A2){
    bf16x8 a0 = *(const bf16x8*)&m.A2[(size_t)rowc*64 + quad*8];
    bf16x8 a1 = *(const bf16x8*)&m.A2[(size_t)rowc*64 + 32 + quad*8];
    #pragma unroll
    for(int t = 0; t < 4; t++){
      bf16x8 b0 = *(const bf16x8*)&Wt2[(t*16 + m16)*72 + quad*8];
      bf16x8 b1 = *(const bf16x8*)&Wt2[(t*16 + m16)*72 + 32 + quad*8];
      acc[t] = __builtin_amdgcn_mfma_f32_16x16x32_bf16(a0, b0, acc[t], 0, 0, 0);
      acc[t] = __builtin_amdgcn_mfma_f32_16x16x32_bf16(a1, b1, acc[t], 0, 0, 0);
    }
  }
  if(m.ep == 3){
    float v[4][4], n2[4] = {0,0,0,0};
    #pragma unroll
    for(int t = 0; t < 4; t++){
      float bv = m.b[t*16 + m16];
      #pragma unroll
      for(int r = 0; r < 4; r++){ v[t][r] = acc[t][r] + bv; n2[r] = fmaf(v[t][r], v[t][r], n2[r]); }
    }
    #pragma unroll
    for(int d = 8; d >= 1; d >>= 1){
      #pragma unroll
      for(int r = 0; r < 4; r++) n2[r] += __shfl_xor(n2[r], d, 64);
    }
    float inv[4];
    #pragma unroll
    for(int r = 0; r < 4; r++) inv[r] = 1.0f / fmaxf(sqrtf(n2[r]), 1e-12f);
    #pragma unroll
    for(int t = 0; t < 4; t++){
      #pragma unroll
      for(int r = 0; r < 4; r++){
        int ro = robase + r;
        if(ro < N) m.C[(size_t)ro*64 + t*16 + m16] = f2bf(fmaxf(v[t][r]*inv[r], 0.f));
      }
    }
    return;
  }
  // ep == 1: BN + relu
  #pragma unroll
  for(int t = 0; t < 4; t++){
    int col = t*16 + m16;
    float bv = m.b[col];
    float gm = m.p1[col]*rsqrtf(1.0f + 1e-5f);
    float be = m.p2[col];
    #pragma unroll
    for(int r = 0; r < 4; r++){
      int ro = robase + r;
      if(ro < N){
        m.C[(size_t)ro*64 + col] = f2bf(fmaxf((acc[t][r] + bv)*gm + be, 0.f));
      }
    }
  }
}

// ---------------- final: GCN2 mm + SAGE2 dual mm + L2norm + GAT2 add + gate combine ----------------
__global__ __launch_bounds__(256) void k_mm_final(
    const unsigned short* __restrict__ A2agg, const unsigned short* __restrict__ wb_gcn2,
    const float* __restrict__ gcn_b2,
    const unsigned short* __restrict__ S2agg, const unsigned short* __restrict__ wb_wl2,
    const float* __restrict__ bl2,
    const unsigned short* __restrict__ s1, const unsigned short* __restrict__ wb_wr2,
    const unsigned short* __restrict__ T2, const float* __restrict__ gat_b2,
    const float* __restrict__ gatew, float* __restrict__ out, int N){
  __shared__ unsigned short W1s[64*72];
  __shared__ unsigned short W2s[64*72];
  __shared__ unsigned short W3s[64*72];
  int tid = threadIdx.x;
  stage_tab(W1s, wb_gcn2, tid);
  stage_tab(W2s, wb_wl2, tid);
  stage_tab(W3s, wb_wr2, tid);
  __syncthreads();
  int w = tid >> 6, lane = tid & 63, quad = lane >> 4, m16 = lane & 15;
  int rowa = blockIdx.x*64 + w*16 + m16;
  int rowc = rowa < N ? rowa : N - 1;
  f32x4 accg[4], accs[4];
  #pragma unroll
  for(int t = 0; t < 4; t++){
    accg[t][0]=0.f; accg[t][1]=0.f; accg[t][2]=0.f; accg[t][3]=0.f;
    accs[t][0]=0.f; accs[t][1]=0.f; accs[t][2]=0.f; accs[t][3]=0.f;
  }
  {
    bf16x8 a0 = *(const bf16x8*)&A2agg[(size_t)rowc*64 + quad*8];
    bf16x8 a1 = *(const bf16x8*)&A2agg[(size_t)rowc*64 + 32 + quad*8];
    #pragma unroll
    for(int t = 0; t < 4; t++){
      bf16x8 b0 = *(const bf16x8*)&W1s[(t*16 + m16)*72 + quad*8];
      bf16x8 b1 = *(const bf16x8*)&W1s[(t*16 + m16)*72 + 32 + quad*8];
      accg[t] = __builtin_amdgcn_mfma_f32_16x16x32_bf16(a0, b0, accg[t], 0, 0, 0);
      accg[t] = __builtin_amdgcn_mfma_f32_16x16x32_bf16(a1, b1, accg[t], 0, 0, 0);
    }
  }
  {
    bf16x8 a0 = *(const bf16x8*)&S2agg[(size_t)rowc*64 + quad*8];
    bf16x8 a1 = *(const bf16x8*)&S2agg[(size_t)rowc*64 + 32 + quad*8];
    #pragma unroll
    for(int t = 0; t < 4; t++){
      bf16x8 b0 = *(const bf16x8*)&W2s[(t*16 + m16)*72 + quad*8];
      bf16x8 b1 = *(const bf16x8*)&W2s[(t*16 + m16)*72 + 32 + quad*8];
      accs[t] = __builtin_amdgcn_mfma_f32_16x16x32_bf16(a0, b0, accs[t], 0, 0, 0);
      accs[t] = __builtin_amdgcn_mfma_f32_16x16x32_bf16(a1, b1, accs[t], 0, 0, 0);
    }
  }
  {
    bf16x8 a0 = *(const bf16x8*)&s1[(size_t)rowc*64 + quad*8];
    bf16x8 a1 = *(const bf16x8*)&s1[(size_t)rowc*64 + 32 + quad*8];
    #pragma unroll
    for(int t = 0; t < 4; t++){
      bf16x8 b0 = *(const bf16x8*)&W3s[(t*16 + m16)*72 + quad*8];
      bf16x8 b1 = *(const bf16x8*)&W3s[(t*16 + m16)*72 + 32 + quad*8];
      accs[t] = __builtin_amdgcn_mfma_f32_16x16x32_bf16(a0, b0, accs[t], 0, 0, 0);
      accs[t] = __builtin_amdgcn_mfma_f32_16x16x32_bf16(a1, b1, accs[t], 0, 0, 0);
    }
  }
  float w0 = gatew[0], w1 = gatew[1], w2 = gatew[2];
  int robase = blockIdx.x*64 + w*16 + quad*4;
  float vs[4][4], n2[4] = {0,0,0,0};
  #pragma unroll
  for(int t = 0; t < 4; t++){
    float bsv = bl2[t*16 + m16];
    #pragma unroll
    for(int r = 0; r < 4; r++){ vs[t][r] = accs[t][r] + bsv; n2[r] = fmaf(vs[t][r], vs[t][r], n2[r]); }
  }
  #pragma unroll
  for(int d = 8; d >= 1; d >>= 1){
    #pragma unroll
    for(int r = 0; r < 4; r++) n2[r] += __shfl_xor(n2[r], d, 64);
  }
  float inv[4];
  #pragma unroll
  for(int r = 0; r < 4; r++) inv[r] = 1.0f / fmaxf(sqrtf(n2[r]), 1e-12f);
  #pragma unroll
  for(int t = 0; t < 4; t++){
    int col = t*16 + m16;
    float bg = gcn_b2[col], bt = gat_b2[col];
    #pragma unroll
    for(int r = 0; r < 4; r++){
      int ro = robase + r;
      if(ro < N){
        float t2 = bflo((unsigned int)T2[(size_t)ro*64 + col]);
        out[(size_t)ro*64 + col] = w0*(accg[t][r] + bg) + w1*(t2 + bt) + w2*vs[t][r]*inv[r];
      }
    }
  }
}

// ---------------- host ----------------
extern "C" void kernel_launch(void* const* d_in, const int* in_sizes, int n_in,
                              void* d_out, int out_size, void* d_ws, size_t ws_size,
                              hipStream_t stream){
  const float* x        = (const float*)d_in[0];
  const int*   ei       = (const int*)d_in[1];
  const int*   row      = ei;
  const int*   col      = ei + NE;
  const float* gate_w1  = (const float*)d_in[2];
  const float* gate_b1  = (const float*)d_in[3];
  const float* gate_w2  = (const float*)d_in[4];
  const float* gate_b2  = (const float*)d_in[5];
  const float* gcn_w1   = (const float*)d_in[6];
  const float* gcn_b1   = (const float*)d_in[7];
  const float* bn_gamma = (const float*)d_in[8];
  const float* bn_beta  = (const float*)d_in[9];
  const float* gcn_w2   = (const float*)d_in[10];
  const float* gcn_b2   = (const float*)d_in[11];
  const float* gat_w1   = (const float*)d_in[12];
  const float* gat_as1  = (const float*)d_in[13];
  const float* gat_ad1  = (const float*)d_in[14];
  const float* gat_b1   = (const float*)d_in[15];
  const float* gat_w2   = (const float*)d_in[16];
  const float* gat_as2  = (const float*)d_in[17];
  const float* gat_ad2  = (const float*)d_in[18];
  const float* gat_b2   = (const float*)d_in[19];
  const float* sage_wl1 = (const float*)d_in[20];
  const float* sage_bl1 = (const float*)d_in[21];
  const float* sage_wr1 = (const float*)d_in[22];
  const float* sage_wl2 = (const float*)d_in[23];
  const float* sage_bl2 = (const float*)d_in[24];
  const float* sage_wr2 = (const float*)d_in[25];
  float* out = (float*)d_out;

  char* wp = (char*)d_ws;
  auto alloc = [&](size_t bytes)->char*{ char* p = wp; wp += (bytes + 255) & ~(size_t)255; return p; };
  // zero-init region (contiguous): cnt, cursor, gsum, total
  int*   cnt    = (int*)  alloc((size_t)NN*4);
  int*   cursor = (int*)  alloc((size_t)NN*4);
  float* gsum   = (float*)alloc(64*4);
  int*   total  = (int*)  alloc(256);
  size_t zbytes = (size_t)(wp - (char*)cnt);
  int*   offs   = (int*)  alloc((size_t)NN*4);
  int*   csr    = (int*)  alloc((size_t)NE*4);
  float* dis    = (float*)alloc((size_t)NN*4);
  float* invc   = (float*)alloc((size_t)NN*4);
  float* gatew  = (float*)alloc(16);
  float* wsd    = (float*)alloc(64*8*4);
  float* pa1    = (float*)alloc((size_t)NN*8*4);
  float* adst1  = (float*)alloc((size_t)NN*4*4);
  float* pa2    = (float*)alloc((size_t)NN*4*4);
  unsigned short* xb     = (unsigned short*)alloc((size_t)NN*64*2);
  unsigned short* z      = (unsigned short*)alloc((size_t)NN*256*2);
  unsigned short* agcnx  = (unsigned short*)alloc((size_t)NN*64*2);
  unsigned short* asagex = (unsigned short*)alloc((size_t)NN*64*2);
  unsigned short* a1     = (unsigned short*)alloc((size_t)NN*64*2);
  unsigned short* s1     = (unsigned short*)alloc((size_t)NN*64*2);
  unsigned short* h2     = (unsigned short*)alloc((size_t)NN*64*2);
  unsigned short* A2agg  = (unsigned short*)alloc((size_t)NN*64*2);
  unsigned short* S2agg  = (unsigned short*)alloc((size_t)NN*64*2);
  unsigned short* T2     = (unsigned short*)alloc((size_t)NN*64*2);
  // packed bf16 weights (B-operand layout [n][K])
  unsigned short* wb_gcn1 = (unsigned short*)alloc((size_t)64*64*2);
  unsigned short* wb_wl1  = (unsigned short*)alloc((size_t)64*64*2);
  unsigned short* wb_wr1  = (unsigned short*)alloc((size_t)64*64*2);
  unsigned short* wb_gat1 = (unsigned short*)alloc((size_t)256*64*2);
  unsigned short* wb_gat2 = (unsigned short*)alloc((size_t)64*256*2);
  unsigned short* wb_gcn2 = (unsigned short*)alloc((size_t)64*64*2);
  unsigned short* wb_wl2  = (unsigned short*)alloc((size_t)64*64*2);
  unsigned short* wb_wr2  = (unsigned short*)alloc((size_t)64*64*2);

  hipMemsetAsync(cnt, 0, zbytes, stream);

  const int gN  = (NN + 63) / 64;   // 782
  const int g4  = NN / 4;           // 12500
  const int gA  = (NN + 255) / 256; // 196

  // ---- pre: packw | count | castsum | fold1 ----
  {
    PreP p = {};
    p.pk[0]  = {gcn_w1,   wb_gcn1,            6, 64,  0};
    p.pk[1]  = {sage_wl1, wb_wl1,             6, 64,  0};
    p.pk[2]  = {sage_wr1, wb_wr1,             6, 64,  0};
    p.pk[3]  = {gat_w1,   wb_gat1 + 0*64*64,  6, 256, 0};
    p.pk[4]  = {gat_w1,   wb_gat1 + 1*64*64,  6, 256, 64};
    p.pk[5]  = {gat_w1,   wb_gat1 + 2*64*64,  6, 256, 128};
    p.pk[6]  = {gat_w1,   wb_gat1 + 3*64*64,  6, 256, 192};
    p.pk[7]  = {gat_w2,   wb_gat2,            8, 64,  0};
    p.pk[8]  = {gcn_w2,   wb_gcn2,            6, 64,  0};
    p.pk[9]  = {sage_wl2, wb_wl2,             6, 64,  0};
    p.pk[10] = {sage_wr2, wb_wr2,             6, 64,  0};
    p.col = col; p.cnt = cnt;
    p.x = x; p.xb = xb; p.gsum = gsum;
    p.gw1 = gat_w1; p.gas = gat_as1; p.gad = gat_ad1; p.wsd = wsd;
    k_pre<<<11 + NB_CNT + 256 + 1, 256, 0, stream>>>(p);
  }

  k_alloc<<<gA, 256, 0, stream>>>(cnt, offs, dis, invc, total, NN);

  // ---- mid: fill | gate | attdotx (writes packed pa1) ----
  {
    MidP p = {};
    p.row = row; p.col = col; p.offs = offs; p.cursor = cursor; p.csr = csr;
    p.gsum = gsum; p.w1 = gate_w1; p.b1 = gate_b1; p.w2 = gate_w2; p.b2 = gate_b2;
    p.gatew = gatew;
    p.xb = xb; p.wsd = wsd;
    p.dis = dis; p.invc = invc;
    p.pa1 = pa1; p.adst = adst1;
    k_mid<<<NB_CNT + 1 + NB_ATT, 256, 0, stream>>>(p);
  }

  // ---- layer-1 gather with inline GAT1 edge weights ----
  {
    A1P p = {};
    p.xb = xb; p.pa1 = pa1; p.adst1 = adst1;
    p.offs = offs; p.cnt = cnt; p.csr = csr;
    p.z = z; p.agcnx = agcnx; p.asagex = asagex; p.N = NN;
    k_agg1<<<g4, 256, 0, stream>>>(p);
  }

  // ---- fused: GAT1+GAT2 (y=0), GCN1 mm (y=1), SAGE1 mm (y=2) ----
  {
    FSP p = {};
    p.N = NN;
    p.z = z; p.wb1 = wb_gat1; p.b1 = gat_b1;
    p.wb2 = wb_gat2; p.as2 = gat_as2; p.ad2 = gat_ad2;
    p.h2 = h2; p.pa2 = pa2;
    p.dis = dis; p.invc = invc;
    p.mm[0] = {agcnx, wb_gcn1, nullptr, nullptr, a1, gcn_b1, bn_gamma, bn_beta, 1};
    p.mm[1] = {asagex, wb_wl1, xb, wb_wr1, s1, sage_bl1, nullptr, nullptr, 3};
    k_fused1<<<dim3(gN,3), 256, 0, stream>>>(p);
  }

  // ---- layer-2 gather with inline GAT2 edge weights (packed pa2) ----
  {
    A2P p = {};
    p.a1 = a1; p.s1 = s1; p.h2 = h2; p.pa2 = pa2;
    p.offs = offs; p.cnt = cnt; p.csr = csr;
    p.A2agg = A2agg; p.S2agg = S2agg; p.T2 = T2; p.N = NN;
    k_agg2<<<g4, 256, 0, stream>>>(p);
  }

  // ---- final matmuls + gate combine ----
  k_mm_final<<<gN, 256, 0, stream>>>(A2agg, wb_gcn2, gcn_b2, S2agg, wb_wl2, sage_bl2,
                                     s1, wb_wr2, T2, gat_b2, gatew, out, NN);
}